// Round 10
// baseline (426.013 us; speedup 1.0000x reference)
//
#include <hip/hip_runtime.h>
#include <hip/hip_bf16.h>
#include <math.h>

// Problem constants
#define BB 4
#define NN 4096
#define EE 256
#define HH 1024
#define NW 12
#define NL 13
#define MM (BB * NN)   // 16384 rows

typedef __attribute__((ext_vector_type(8))) short short8;   // 8 bf16 (4 VGPRs)
typedef __attribute__((ext_vector_type(4))) float f32x4;

// Fast gelu, exp2 form: x * sigmoid(1.5957691*(x + 0.044715 x^3)).
__device__ __forceinline__ float gelu_fast(float x) {
    float t = __builtin_fmaf(0.044715f, x * x, 1.0f);
    float e = __builtin_amdgcn_exp2f(-2.3021193f * (x * t));
    return x * __builtin_amdgcn_rcpf(1.0f + e);
}

__device__ __forceinline__ unsigned pack_bf16_rh(float a, float b) {
    unsigned ua = (__builtin_bit_cast(unsigned, a) + 0x8000u) >> 16;
    unsigned ub = (__builtin_bit_cast(unsigned, b) + 0x8000u) & 0xFFFF0000u;
    return ua | ub;
}

__device__ __forceinline__ void unpack2(unsigned u, float& lo, float& hi) {
    lo = __builtin_bit_cast(float, u << 16);
    hi = __builtin_bit_cast(float, u & 0xFFFF0000u);
}

__device__ __forceinline__ void load_lds16(const void* g, void* l) {
    __builtin_amdgcn_global_load_lds(
        (const __attribute__((address_space(1))) void*)g,
        (__attribute__((address_space(3))) void*)l, 16, 0, 0);
}

// ---------------------------------------------------------------------------
// Fused gate MLP (round-7 structure, validated): V0 = gelu(V@W1+b1)@W2+b2.
// ---------------------------------------------------------------------------
__global__ __launch_bounds__(256, 2) void gate_fused(
    const __hip_bfloat16* __restrict__ Vb,    // MM x EE
    const __hip_bfloat16* __restrict__ W1t,   // HH x EE (gW1t)
    const float* __restrict__ b1,             // HH
    const __hip_bfloat16* __restrict__ W2t,   // EE x HH (gW2t)
    const float* __restrict__ b2,             // EE
    __hip_bfloat16* __restrict__ V0)          // MM x EE
{
    __shared__ __hip_bfloat16 Bs[8 * 64 * 32];        // 32 KB [kk][row][32]
    __shared__ __align__(16) char Gb[4][2048];        // per-wave G [16r][64h]
    __shared__ float biasS[HH];                       // 4 KB
    __shared__ float bias2S[EE];                      // 1 KB

    const int tid = threadIdx.x;
    const int w = tid >> 6, l = tid & 63;
    const int row0 = blockIdx.x * 64;
    const int lr = l & 15, g = l >> 4, lk = g * 8;

    ((float4*)biasS)[tid] = ((const float4*)b1)[tid];
    if (tid < EE / 4) ((float4*)bias2S)[tid] = ((const float4*)b2)[tid];

    short8 xf[8];
    {
        const __hip_bfloat16* xp0 = Vb + (size_t)(row0 + w * 16 + lr) * EE + lk;
        #pragma unroll
        for (int kk = 0; kk < 8; ++kk) xf[kk] = *(const short8*)(xp0 + kk * 32);
    }
    char* Gw = Gb[w];
    f32x4 accV[16] = {};

    #pragma unroll
    for (int rstep = 0; rstep < 8; ++rstep) {
        const int c = rstep * 256 + tid;
        load_lds16(W1t + (size_t)((c >> 2) & 63) * EE + (c >> 8) * 32 + (c & 3) * 8,
                   (char*)Bs + c * 16);
    }
    __syncthreads();

    #pragma unroll 1
    for (int ct = 0; ct < 16; ++ct) {
        f32x4 acc[4] = {};
        __builtin_amdgcn_s_setprio(1);
        #pragma unroll
        for (int kk = 0; kk < 8; ++kk) {
            short8 a[4];
            #pragma unroll
            for (int ni = 0; ni < 4; ++ni)
                a[ni] = *(const short8*)((const char*)Bs +
                         (kk * 4096 + ni * 1024 + lr * 64 + g * 16));
            #pragma unroll
            for (int ni = 0; ni < 4; ++ni)
                acc[ni] = __builtin_amdgcn_mfma_f32_16x16x32_bf16(a[ni], xf[kk], acc[ni], 0, 0, 0);
        }
        __builtin_amdgcn_s_setprio(0);
        __syncthreads();

        if (ct < 15) {
            const __hip_bfloat16* W1n = W1t + (size_t)(ct + 1) * 64 * EE;
            #pragma unroll
            for (int rstep = 0; rstep < 8; ++rstep) {
                const int c = rstep * 256 + tid;
                load_lds16(W1n + (size_t)((c >> 2) & 63) * EE + (c >> 8) * 32 + (c & 3) * 8,
                           (char*)Bs + c * 16);
            }
        }

        #pragma unroll
        for (int ni = 0; ni < 4; ++ni) {
            const float4 bv = *(const float4*)&biasS[ct * 64 + ni * 16 + g * 4];
            const float v0 = gelu_fast(acc[ni][0] + bv.x);
            const float v1 = gelu_fast(acc[ni][1] + bv.y);
            const float v2 = gelu_fast(acc[ni][2] + bv.z);
            const float v3 = gelu_fast(acc[ni][3] + bv.w);
            uint2 pk;
            pk.x = pack_bf16_rh(v0, v1);
            pk.y = pack_bf16_rh(v2, v3);
            const int byte = (lr * 128 + (ni * 16 + g * 4) * 2) ^ ((lr & 7) << 4);
            *(uint2*)(Gw + byte) = pk;
        }

        #pragma unroll
        for (int ks2 = 0; ks2 < 2; ++ks2) {
            const int byte = (lr * 128 + (ks2 * 32 + lk) * 2) ^ ((lr & 7) << 4);
            const short8 bg = *(const short8*)(Gw + byte);
            const __hip_bfloat16* wp = W2t + (size_t)lr * HH + ct * 64 + ks2 * 32 + lk;
            #pragma unroll
            for (int et = 0; et < 16; ++et)
                accV[et] = __builtin_amdgcn_mfma_f32_16x16x32_bf16(
                    *(const short8*)(wp + (size_t)et * 16 * HH), bg, accV[et], 0, 0, 0);
        }
        __syncthreads();
    }

    __hip_bfloat16* vp = V0 + (size_t)(row0 + w * 16 + lr) * EE;
    #pragma unroll
    for (int et = 0; et < 16; ++et) {
        const float4 bv = *(const float4*)&bias2S[et * 16 + g * 4];
        uint2 o;
        o.x = pack_bf16_rh(accV[et][0] + bv.x, accV[et][1] + bv.y);
        o.y = pack_bf16_rh(accV[et][2] + bv.z, accV[et][3] + bv.w);
        *(uint2*)(vp + et * 16 + g * 4) = o;
    }
}

// ---------------------------------------------------------------------------
// Fused f-level kernel v4: 256 rows/block, 512 threads (8 waves).
// W1 staging (fixed 512 KB/block) now amortized over 2x rows; per-thread
// staging ops halve; 2 blocks/CU -> 16 waves/CU (was ~9).
// ---------------------------------------------------------------------------
__global__ __launch_bounds__(512, 4) void f_fused(
    const __hip_bfloat16* __restrict__ X,     // MM x EE
    const __hip_bfloat16* __restrict__ W1t,   // NW x HH x EE
    const float* __restrict__ b1,             // NW x HH
    const __hip_bfloat16* __restrict__ W2t,   // NW x 16 x HH
    const float* __restrict__ b2,             // NW x NL
    float* __restrict__ Wall)                 // MM x NW x 16
{
    __shared__ __hip_bfloat16 Bs[8 * 64 * 32];        // 32 KB [kk][row][32]
    __shared__ __align__(16) char Gb[8][4096];        // per-wave G [32r][64h] 32 KB
    __shared__ float biasS[HH];                       // 4 KB

    const int tid = threadIdx.x;
    const int w = tid >> 6, l = tid & 63;             // 8 waves
    const int row0 = blockIdx.x * 256;
    const int m_lv = blockIdx.y;
    const int lr = l & 15;
    const int g  = l >> 4;
    const int lk = g * 8;

    const __hip_bfloat16* W1m = W1t + (size_t)m_lv * HH * EE;

    ((float2*)biasS)[tid] = ((const float2*)(b1 + (size_t)m_lv * HH))[tid];

    short8 xf[2][8];
    {
        const __hip_bfloat16* xp0 = X + (size_t)(row0 + w * 32 + lr) * EE + lk;
        #pragma unroll
        for (int kk = 0; kk < 8; ++kk) {
            xf[0][kk] = *(const short8*)(xp0 + kk * 32);
            xf[1][kk] = *(const short8*)(xp0 + 16 * EE + kk * 32);
        }
    }

    const __hip_bfloat16* w2p = W2t + ((size_t)m_lv * 16 + lr) * HH + lk;
    char* Gw = Gb[w];

    f32x4 wacc0 = {}, wacc1 = {};

    // prologue: stage ct = 0 (chunk c: kk=c>>8, row=(c>>2)&63, g=c&3)
    #pragma unroll
    for (int rstep = 0; rstep < 4; ++rstep) {
        const int c = rstep * 512 + tid;
        load_lds16(W1m + (size_t)((c >> 2) & 63) * EE + (c >> 8) * 32 + (c & 3) * 8,
                   (char*)Bs + c * 16);
    }
    __syncthreads();

    #pragma unroll 1
    for (int ct = 0; ct < 16; ++ct) {
        f32x4 acc[4][2] = {};
        __builtin_amdgcn_s_setprio(1);
        #pragma unroll
        for (int kk = 0; kk < 8; ++kk) {
            short8 a[4];
            #pragma unroll
            for (int ni = 0; ni < 4; ++ni)
                a[ni] = *(const short8*)((const char*)Bs +
                         (kk * 4096 + ni * 1024 + lr * 64 + g * 16));
            #pragma unroll
            for (int ni = 0; ni < 4; ++ni) {
                acc[ni][0] = __builtin_amdgcn_mfma_f32_16x16x32_bf16(a[ni], xf[0][kk], acc[ni][0], 0, 0, 0);
                acc[ni][1] = __builtin_amdgcn_mfma_f32_16x16x32_bf16(a[ni], xf[1][kk], acc[ni][1], 0, 0, 0);
            }
        }
        __builtin_amdgcn_s_setprio(0);
        __syncthreads();                       // all waves done reading Bs

        if (ct < 15) {
            const __hip_bfloat16* W1n = W1m + (size_t)(ct + 1) * 64 * EE;
            #pragma unroll
            for (int rstep = 0; rstep < 4; ++rstep) {
                const int c = rstep * 512 + tid;
                load_lds16(W1n + (size_t)((c >> 2) & 63) * EE + (c >> 8) * 32 + (c & 3) * 8,
                           (char*)Bs + c * 16);
            }
        }

        // gelu + bias -> bf16 pack -> wave-private swizzled G
        #pragma unroll
        for (int ni = 0; ni < 4; ++ni) {
            const float4 bv = *(const float4*)&biasS[ct * 64 + ni * 16 + g * 4];
            #pragma unroll
            for (int mi = 0; mi < 2; ++mi) {
                const int rloc = mi * 16 + lr;
                const float v0 = gelu_fast(acc[ni][mi][0] + bv.x);
                const float v1 = gelu_fast(acc[ni][mi][1] + bv.y);
                const float v2 = gelu_fast(acc[ni][mi][2] + bv.z);
                const float v3 = gelu_fast(acc[ni][mi][3] + bv.w);
                uint2 pk;
                pk.x = pack_bf16_rh(v0, v1);
                pk.y = pack_bf16_rh(v2, v3);
                const int byte = (rloc * 128 + (ni * 16 + g * 4) * 2) ^ ((rloc & 7) << 4);
                *(uint2*)(Gw + byte) = pk;
            }
        }

        // mini-GEMM: Wall-frag += W2t[ct k-range] x G
        #pragma unroll
        for (int ks2 = 0; ks2 < 2; ++ks2) {
            const short8 aw = *(const short8*)(w2p + ct * 64 + ks2 * 32);
            {
                const int byte = (lr * 128 + (ks2 * 32 + lk) * 2) ^ ((lr & 7) << 4);
                const short8 bg = *(const short8*)(Gw + byte);
                wacc0 = __builtin_amdgcn_mfma_f32_16x16x32_bf16(aw, bg, wacc0, 0, 0, 0);
            }
            {
                const int rloc = 16 + lr;
                const int byte = (rloc * 128 + (ks2 * 32 + lk) * 2) ^ ((rloc & 7) << 4);
                const short8 bg = *(const short8*)(Gw + byte);
                wacc1 = __builtin_amdgcn_mfma_f32_16x16x32_bf16(aw, bg, wacc1, 0, 0, 0);
            }
        }
        __syncthreads();                       // staging drained; Bs ready
    }

    const float* b2m = b2 + m_lv * NL;
    #pragma unroll
    for (int j = 0; j < 4; ++j) {
        const int lval = g * 4 + j;
        const float bv = (lval < NL) ? b2m[lval] : 0.f;
        {
            const int r = row0 + w * 32 + lr;
            Wall[((size_t)r * NW + m_lv) * 16 + lval] = wacc0[j] + bv;
        }
        {
            const int r = row0 + w * 32 + 16 + lr;
            Wall[((size_t)r * NW + m_lv) * 16 + lval] = wacc1[j] + bv;
        }
    }
}

// ---------------------------------------------------------------------------
// Converters
// ---------------------------------------------------------------------------
struct bf4 { __hip_bfloat16 a, b, c, d; };

__global__ __launch_bounds__(256) void cvt_bf16(
    const float* __restrict__ in, __hip_bfloat16* __restrict__ out, int n4)
{
    int i = blockIdx.x * 256 + threadIdx.x;
    if (i >= n4) return;
    float4 v = ((const float4*)in)[i];
    bf4 o;
    o.a = __float2bfloat16(v.x); o.b = __float2bfloat16(v.y);
    o.c = __float2bfloat16(v.z); o.d = __float2bfloat16(v.w);
    ((bf4*)out)[i] = o;
}

__global__ __launch_bounds__(256) void transpose_cvt(
    const float* __restrict__ in, __hip_bfloat16* __restrict__ out, int K, int N)
{
    __shared__ float t[32][33];
    const int bz = blockIdx.z;
    const float* inB = in + (size_t)bz * K * N;
    __hip_bfloat16* outB = out + (size_t)bz * K * N;
    const int n0 = blockIdx.x * 32, k0 = blockIdx.y * 32;
    const int tx = threadIdx.x & 31, ty = threadIdx.x >> 5;
    #pragma unroll
    for (int i = 0; i < 32; i += 8)
        t[ty + i][tx] = inB[(size_t)(k0 + ty + i) * N + n0 + tx];
    __syncthreads();
    #pragma unroll
    for (int i = 0; i < 32; i += 8)
        outB[(size_t)(n0 + ty + i) * K + k0 + tx] = __float2bfloat16(t[tx][ty + i]);
}

__global__ __launch_bounds__(256) void w2t_cvt(
    const float* __restrict__ f_W2, __hip_bfloat16* __restrict__ W2t)
{
    int idx = blockIdx.x * 256 + threadIdx.x;
    if (idx >= NW * 16 * HH) return;
    const int m = idx >> 14;
    const int n = (idx >> 10) & 15;
    const int h = idx & 1023;
    const float v = (n < NL) ? f_W2[((size_t)m * HH + h) * NL + n] : 0.f;
    W2t[idx] = __float2bfloat16(v);
}

// ---------------------------------------------------------------------------
// Chord step, bf16 state, f32 accumulation, XCD-chunk swizzle: each XCD gets
// a contiguous 2048-row (half-batch) range so all +-2^l gathers stay inside
// that batch's 2 MB, which fits the XCD's private 4 MB L2.
// ---------------------------------------------------------------------------
template<bool LAST>
__global__ __launch_bounds__(256) void chord_bf16(
    const uint2* __restrict__ Vin,   // MM x 64 (4 bf16 per lane-slot)
    const float* __restrict__ Wall,  // MM x NW x 16
    void* __restrict__ Vout,         // bf16 (MM x 64 uint2) or f32 (float4)
    int m)
{
    const int t = threadIdx.x;
    const int bid = blockIdx.x;                      // 4096 blocks
    const int swz = (bid & 7) * 512 + (bid >> 3);    // XCD-contiguous chunks
    const int r = swz * 4 + (t >> 6);
    const int e = t & 63;
    const int b = r >> 12;
    const int n = r & (NN - 1);

    const float* wrow = Wall + ((size_t)r * NW + m) * 16;
    const size_t base = (size_t)(b << 12) * 64 + e;

    uint2 s = Vin[(size_t)r * 64 + e];
    float a0, a1, a2, a3;
    unpack2(s.x, a0, a1);
    unpack2(s.y, a2, a3);

    #pragma unroll
    for (int l = 0; l < NL; ++l) {
        const int off = (l == 0) ? 0 : (1 << (l - 1));
        const int cn = (n + off) & (NN - 1);
        const float wv = wrow[l];
        const uint2 x = Vin[base + (size_t)cn * 64];
        float x0, x1, x2, x3;
        unpack2(x.x, x0, x1);
        unpack2(x.y, x2, x3);
        a0 = __builtin_fmaf(wv, x0, a0);
        a1 = __builtin_fmaf(wv, x1, a1);
        a2 = __builtin_fmaf(wv, x2, a2);
        a3 = __builtin_fmaf(wv, x3, a3);
    }

    if constexpr (LAST) {
        float4 o = {a0, a1, a2, a3};
        ((float4*)Vout)[(size_t)r * 64 + e] = o;
    } else {
        uint2 o;
        o.x = pack_bf16_rh(a0, a1);
        o.y = pack_bf16_rh(a2, a3);
        ((uint2*)Vout)[(size_t)r * 64 + e] = o;
    }
}

// ---------------------------------------------------------------------------
extern "C" void kernel_launch(void* const* d_in, const int* in_sizes, int n_in,
                              void* d_out, int out_size, void* d_ws, size_t ws_size,
                              hipStream_t stream)
{
    const float* V      = (const float*)d_in[0];
    const float* input  = (const float*)d_in[1];
    const float* g_W1   = (const float*)d_in[2];
    const float* g_b1   = (const float*)d_in[3];
    const float* g_W2   = (const float*)d_in[4];
    const float* g_b2   = (const float*)d_in[5];
    const float* f_W1   = (const float*)d_in[6];
    const float* f_b1   = (const float*)d_in[7];
    const float* f_W2   = (const float*)d_in[8];
    const float* f_b2   = (const float*)d_in[9];
    float* out = (float*)d_out;

    char* ws = (char*)d_ws;
    size_t o = 0;
    __hip_bfloat16* Vb     = (__hip_bfloat16*)(ws + o); o += (size_t)MM * EE * 2;        // 8 MB
    __hip_bfloat16* Xb     = (__hip_bfloat16*)(ws + o); o += (size_t)MM * EE * 2;        // 8 MB
    __hip_bfloat16* gW1t   = (__hip_bfloat16*)(ws + o); o += (size_t)HH * EE * 2;        // 512 KB
    __hip_bfloat16* gW2t   = (__hip_bfloat16*)(ws + o); o += (size_t)EE * HH * 2;        // 512 KB
    __hip_bfloat16* fW1t   = (__hip_bfloat16*)(ws + o); o += (size_t)NW * HH * EE * 2;   // 6 MB
    __hip_bfloat16* W2tA   = (__hip_bfloat16*)(ws + o); o += (size_t)NW * 16 * HH * 2;   // 384 KB
    float*          Wall   = (float*)(ws + o);          o += (size_t)MM * NW * 16 * 4;   // 12 MB
    __hip_bfloat16* Vg0    = (__hip_bfloat16*)(ws + o); o += (size_t)MM * EE * 2;        // 8 MB
    __hip_bfloat16* Vg1    = (__hip_bfloat16*)(ws + o); o += (size_t)MM * EE * 2;        // 8 MB

    dim3 blk(256);

    // 0. dtype conversion / weight transposes
    cvt_bf16<<<(MM * EE / 4 + 255) / 256, blk, 0, stream>>>(V, Vb, MM * EE / 4);
    cvt_bf16<<<(MM * EE / 4 + 255) / 256, blk, 0, stream>>>(input, Xb, MM * EE / 4);
    transpose_cvt<<<dim3(HH / 32, EE / 32, 1),  blk, 0, stream>>>(g_W1, gW1t, EE, HH);
    transpose_cvt<<<dim3(EE / 32, HH / 32, 1),  blk, 0, stream>>>(g_W2, gW2t, HH, EE);
    transpose_cvt<<<dim3(HH / 32, EE / 32, NW), blk, 0, stream>>>(f_W1, fW1t, EE, HH);
    w2t_cvt<<<(NW * 16 * HH + 255) / 256, blk, 0, stream>>>(f_W2, W2tA);

    // 1. Gate MLP on V, fully fused, bf16 V0 -> Vg0
    gate_fused<<<MM / 64, blk, 0, stream>>>(Vb, gW1t, g_b1, gW2t, g_b2, Vg0);

    // 2. All 12 levels' link weights in ONE fused launch (256 rows/block)
    f_fused<<<dim3(MM / 256, NW), dim3(512), 0, stream>>>(
        Xb, fW1t, f_b1, W2tA, f_b2, Wall);

    // 3. 12 sequential chord steps, stream-ordered; final widens to f32 out
    const __hip_bfloat16* cur = Vg0;
    __hip_bfloat16* nxt = Vg1;
    for (int m = 0; m < NW - 1; ++m) {
        chord_bf16<false><<<MM / 4, blk, 0, stream>>>(
            (const uint2*)cur, Wall, nxt, m);
        __hip_bfloat16* tswap = (__hip_bfloat16*)cur;
        cur = nxt;
        nxt = tswap;
    }
    chord_bf16<true><<<MM / 4, blk, 0, stream>>>(
        (const uint2*)cur, Wall, out, NW - 1);
}

// Round 11
// 409.845 us; speedup vs baseline: 1.0394x; 1.0394x over previous
//
#include <hip/hip_runtime.h>
#include <hip/hip_bf16.h>
#include <math.h>

// Problem constants
#define BB 4
#define NN 4096
#define EE 256
#define HH 1024
#define NW 12
#define NL 13
#define MM (BB * NN)   // 16384 rows

typedef __attribute__((ext_vector_type(8))) short short8;   // 8 bf16 (4 VGPRs)
typedef __attribute__((ext_vector_type(4))) float f32x4;

// Fast gelu, exp2 form: x * sigmoid(1.5957691*(x + 0.044715 x^3)).
__device__ __forceinline__ float gelu_fast(float x) {
    float t = __builtin_fmaf(0.044715f, x * x, 1.0f);
    float e = __builtin_amdgcn_exp2f(-2.3021193f * (x * t));
    return x * __builtin_amdgcn_rcpf(1.0f + e);
}

__device__ __forceinline__ unsigned pack_bf16_rh(float a, float b) {
    unsigned ua = (__builtin_bit_cast(unsigned, a) + 0x8000u) >> 16;
    unsigned ub = (__builtin_bit_cast(unsigned, b) + 0x8000u) & 0xFFFF0000u;
    return ua | ub;
}

__device__ __forceinline__ void unpack2(unsigned u, float& lo, float& hi) {
    lo = __builtin_bit_cast(float, u << 16);
    hi = __builtin_bit_cast(float, u & 0xFFFF0000u);
}

__device__ __forceinline__ void load_lds16(const void* g, void* l) {
    __builtin_amdgcn_global_load_lds(
        (const __attribute__((address_space(1))) void*)g,
        (__attribute__((address_space(3))) void*)l, 16, 0, 0);
}

// ---------------------------------------------------------------------------
// Fused gate MLP (round-7 structure, validated): V0 = gelu(V@W1+b1)@W2+b2.
// ---------------------------------------------------------------------------
__global__ __launch_bounds__(256, 2) void gate_fused(
    const __hip_bfloat16* __restrict__ Vb,    // MM x EE
    const __hip_bfloat16* __restrict__ W1t,   // HH x EE (gW1t)
    const float* __restrict__ b1,             // HH
    const __hip_bfloat16* __restrict__ W2t,   // EE x HH (gW2t)
    const float* __restrict__ b2,             // EE
    __hip_bfloat16* __restrict__ V0)          // MM x EE
{
    __shared__ __hip_bfloat16 Bs[8 * 64 * 32];        // 32 KB [kk][row][32]
    __shared__ __align__(16) char Gb[4][2048];        // per-wave G [16r][64h]
    __shared__ float biasS[HH];                       // 4 KB
    __shared__ float bias2S[EE];                      // 1 KB

    const int tid = threadIdx.x;
    const int w = tid >> 6, l = tid & 63;
    const int row0 = blockIdx.x * 64;
    const int lr = l & 15, g = l >> 4, lk = g * 8;

    ((float4*)biasS)[tid] = ((const float4*)b1)[tid];
    if (tid < EE / 4) ((float4*)bias2S)[tid] = ((const float4*)b2)[tid];

    short8 xf[8];
    {
        const __hip_bfloat16* xp0 = Vb + (size_t)(row0 + w * 16 + lr) * EE + lk;
        #pragma unroll
        for (int kk = 0; kk < 8; ++kk) xf[kk] = *(const short8*)(xp0 + kk * 32);
    }
    char* Gw = Gb[w];
    f32x4 accV[16] = {};

    #pragma unroll
    for (int rstep = 0; rstep < 8; ++rstep) {
        const int c = rstep * 256 + tid;
        load_lds16(W1t + (size_t)((c >> 2) & 63) * EE + (c >> 8) * 32 + (c & 3) * 8,
                   (char*)Bs + c * 16);
    }
    __syncthreads();

    #pragma unroll 1
    for (int ct = 0; ct < 16; ++ct) {
        f32x4 acc[4] = {};
        __builtin_amdgcn_s_setprio(1);
        #pragma unroll
        for (int kk = 0; kk < 8; ++kk) {
            short8 a[4];
            #pragma unroll
            for (int ni = 0; ni < 4; ++ni)
                a[ni] = *(const short8*)((const char*)Bs +
                         (kk * 4096 + ni * 1024 + lr * 64 + g * 16));
            #pragma unroll
            for (int ni = 0; ni < 4; ++ni)
                acc[ni] = __builtin_amdgcn_mfma_f32_16x16x32_bf16(a[ni], xf[kk], acc[ni], 0, 0, 0);
        }
        __builtin_amdgcn_s_setprio(0);
        __syncthreads();

        if (ct < 15) {
            const __hip_bfloat16* W1n = W1t + (size_t)(ct + 1) * 64 * EE;
            #pragma unroll
            for (int rstep = 0; rstep < 8; ++rstep) {
                const int c = rstep * 256 + tid;
                load_lds16(W1n + (size_t)((c >> 2) & 63) * EE + (c >> 8) * 32 + (c & 3) * 8,
                           (char*)Bs + c * 16);
            }
        }

        #pragma unroll
        for (int ni = 0; ni < 4; ++ni) {
            const float4 bv = *(const float4*)&biasS[ct * 64 + ni * 16 + g * 4];
            const float v0 = gelu_fast(acc[ni][0] + bv.x);
            const float v1 = gelu_fast(acc[ni][1] + bv.y);
            const float v2 = gelu_fast(acc[ni][2] + bv.z);
            const float v3 = gelu_fast(acc[ni][3] + bv.w);
            uint2 pk;
            pk.x = pack_bf16_rh(v0, v1);
            pk.y = pack_bf16_rh(v2, v3);
            const int byte = (lr * 128 + (ni * 16 + g * 4) * 2) ^ ((lr & 7) << 4);
            *(uint2*)(Gw + byte) = pk;
        }

        #pragma unroll
        for (int ks2 = 0; ks2 < 2; ++ks2) {
            const int byte = (lr * 128 + (ks2 * 32 + lk) * 2) ^ ((lr & 7) << 4);
            const short8 bg = *(const short8*)(Gw + byte);
            const __hip_bfloat16* wp = W2t + (size_t)lr * HH + ct * 64 + ks2 * 32 + lk;
            #pragma unroll
            for (int et = 0; et < 16; ++et)
                accV[et] = __builtin_amdgcn_mfma_f32_16x16x32_bf16(
                    *(const short8*)(wp + (size_t)et * 16 * HH), bg, accV[et], 0, 0, 0);
        }
        __syncthreads();
    }

    __hip_bfloat16* vp = V0 + (size_t)(row0 + w * 16 + lr) * EE;
    #pragma unroll
    for (int et = 0; et < 16; ++et) {
        const float4 bv = *(const float4*)&bias2S[et * 16 + g * 4];
        uint2 o;
        o.x = pack_bf16_rh(accV[et][0] + bv.x, accV[et][1] + bv.y);
        o.y = pack_bf16_rh(accV[et][2] + bv.z, accV[et][3] + bv.w);
        *(uint2*)(vp + et * 16 + g * 4) = o;
    }
}

// ---------------------------------------------------------------------------
// Fused f-level kernel v4b: 256 rows/block, 512 threads (8 waves),
// __launch_bounds__(512, 2): 256-VGPR cap -> no spill (the (512,4) variant
// capped arch-VGPRs at 64 and spilled ~40 MB/dispatch to scratch).
// LDS 68 KB -> 2 blocks/CU when VGPR <= 128 (per-thread state ~= v3's 84).
// ---------------------------------------------------------------------------
__global__ __launch_bounds__(512, 2) void f_fused(
    const __hip_bfloat16* __restrict__ X,     // MM x EE
    const __hip_bfloat16* __restrict__ W1t,   // NW x HH x EE
    const float* __restrict__ b1,             // NW x HH
    const __hip_bfloat16* __restrict__ W2t,   // NW x 16 x HH
    const float* __restrict__ b2,             // NW x NL
    float* __restrict__ Wall)                 // MM x NW x 16
{
    __shared__ __hip_bfloat16 Bs[8 * 64 * 32];        // 32 KB [kk][row][32]
    __shared__ __align__(16) char Gb[8][4096];        // per-wave G [32r][64h] 32 KB
    __shared__ float biasS[HH];                       // 4 KB

    const int tid = threadIdx.x;
    const int w = tid >> 6, l = tid & 63;             // 8 waves
    const int row0 = blockIdx.x * 256;
    const int m_lv = blockIdx.y;
    const int lr = l & 15;
    const int g  = l >> 4;
    const int lk = g * 8;

    const __hip_bfloat16* W1m = W1t + (size_t)m_lv * HH * EE;

    ((float2*)biasS)[tid] = ((const float2*)(b1 + (size_t)m_lv * HH))[tid];

    short8 xf[2][8];
    {
        const __hip_bfloat16* xp0 = X + (size_t)(row0 + w * 32 + lr) * EE + lk;
        #pragma unroll
        for (int kk = 0; kk < 8; ++kk) {
            xf[0][kk] = *(const short8*)(xp0 + kk * 32);
            xf[1][kk] = *(const short8*)(xp0 + 16 * EE + kk * 32);
        }
    }

    const __hip_bfloat16* w2p = W2t + ((size_t)m_lv * 16 + lr) * HH + lk;
    char* Gw = Gb[w];

    f32x4 wacc0 = {}, wacc1 = {};

    // prologue: stage ct = 0 (chunk c: kk=c>>8, row=(c>>2)&63, g=c&3)
    #pragma unroll
    for (int rstep = 0; rstep < 4; ++rstep) {
        const int c = rstep * 512 + tid;
        load_lds16(W1m + (size_t)((c >> 2) & 63) * EE + (c >> 8) * 32 + (c & 3) * 8,
                   (char*)Bs + c * 16);
    }
    __syncthreads();

    #pragma unroll 1
    for (int ct = 0; ct < 16; ++ct) {
        f32x4 acc[4][2] = {};
        __builtin_amdgcn_s_setprio(1);
        #pragma unroll
        for (int kk = 0; kk < 8; ++kk) {
            short8 a[4];
            #pragma unroll
            for (int ni = 0; ni < 4; ++ni)
                a[ni] = *(const short8*)((const char*)Bs +
                         (kk * 4096 + ni * 1024 + lr * 64 + g * 16));
            #pragma unroll
            for (int ni = 0; ni < 4; ++ni) {
                acc[ni][0] = __builtin_amdgcn_mfma_f32_16x16x32_bf16(a[ni], xf[0][kk], acc[ni][0], 0, 0, 0);
                acc[ni][1] = __builtin_amdgcn_mfma_f32_16x16x32_bf16(a[ni], xf[1][kk], acc[ni][1], 0, 0, 0);
            }
        }
        __builtin_amdgcn_s_setprio(0);
        __syncthreads();                       // all waves done reading Bs

        if (ct < 15) {
            const __hip_bfloat16* W1n = W1m + (size_t)(ct + 1) * 64 * EE;
            #pragma unroll
            for (int rstep = 0; rstep < 4; ++rstep) {
                const int c = rstep * 512 + tid;
                load_lds16(W1n + (size_t)((c >> 2) & 63) * EE + (c >> 8) * 32 + (c & 3) * 8,
                           (char*)Bs + c * 16);
            }
        }

        // gelu + bias -> bf16 pack -> wave-private swizzled G
        #pragma unroll
        for (int ni = 0; ni < 4; ++ni) {
            const float4 bv = *(const float4*)&biasS[ct * 64 + ni * 16 + g * 4];
            #pragma unroll
            for (int mi = 0; mi < 2; ++mi) {
                const int rloc = mi * 16 + lr;
                const float v0 = gelu_fast(acc[ni][mi][0] + bv.x);
                const float v1 = gelu_fast(acc[ni][mi][1] + bv.y);
                const float v2 = gelu_fast(acc[ni][mi][2] + bv.z);
                const float v3 = gelu_fast(acc[ni][mi][3] + bv.w);
                uint2 pk;
                pk.x = pack_bf16_rh(v0, v1);
                pk.y = pack_bf16_rh(v2, v3);
                const int byte = (rloc * 128 + (ni * 16 + g * 4) * 2) ^ ((rloc & 7) << 4);
                *(uint2*)(Gw + byte) = pk;
            }
        }

        // mini-GEMM: Wall-frag += W2t[ct k-range] x G
        #pragma unroll
        for (int ks2 = 0; ks2 < 2; ++ks2) {
            const short8 aw = *(const short8*)(w2p + ct * 64 + ks2 * 32);
            {
                const int byte = (lr * 128 + (ks2 * 32 + lk) * 2) ^ ((lr & 7) << 4);
                const short8 bg = *(const short8*)(Gw + byte);
                wacc0 = __builtin_amdgcn_mfma_f32_16x16x32_bf16(aw, bg, wacc0, 0, 0, 0);
            }
            {
                const int rloc = 16 + lr;
                const int byte = (rloc * 128 + (ks2 * 32 + lk) * 2) ^ ((rloc & 7) << 4);
                const short8 bg = *(const short8*)(Gw + byte);
                wacc1 = __builtin_amdgcn_mfma_f32_16x16x32_bf16(aw, bg, wacc1, 0, 0, 0);
            }
        }
        __syncthreads();                       // staging drained; Bs ready
    }

    const float* b2m = b2 + m_lv * NL;
    #pragma unroll
    for (int j = 0; j < 4; ++j) {
        const int lval = g * 4 + j;
        const float bv = (lval < NL) ? b2m[lval] : 0.f;
        {
            const int r = row0 + w * 32 + lr;
            Wall[((size_t)r * NW + m_lv) * 16 + lval] = wacc0[j] + bv;
        }
        {
            const int r = row0 + w * 32 + 16 + lr;
            Wall[((size_t)r * NW + m_lv) * 16 + lval] = wacc1[j] + bv;
        }
    }
}

// ---------------------------------------------------------------------------
// Converters
// ---------------------------------------------------------------------------
struct bf4 { __hip_bfloat16 a, b, c, d; };

__global__ __launch_bounds__(256) void cvt_bf16(
    const float* __restrict__ in, __hip_bfloat16* __restrict__ out, int n4)
{
    int i = blockIdx.x * 256 + threadIdx.x;
    if (i >= n4) return;
    float4 v = ((const float4*)in)[i];
    bf4 o;
    o.a = __float2bfloat16(v.x); o.b = __float2bfloat16(v.y);
    o.c = __float2bfloat16(v.z); o.d = __float2bfloat16(v.w);
    ((bf4*)out)[i] = o;
}

__global__ __launch_bounds__(256) void transpose_cvt(
    const float* __restrict__ in, __hip_bfloat16* __restrict__ out, int K, int N)
{
    __shared__ float t[32][33];
    const int bz = blockIdx.z;
    const float* inB = in + (size_t)bz * K * N;
    __hip_bfloat16* outB = out + (size_t)bz * K * N;
    const int n0 = blockIdx.x * 32, k0 = blockIdx.y * 32;
    const int tx = threadIdx.x & 31, ty = threadIdx.x >> 5;
    #pragma unroll
    for (int i = 0; i < 32; i += 8)
        t[ty + i][tx] = inB[(size_t)(k0 + ty + i) * N + n0 + tx];
    __syncthreads();
    #pragma unroll
    for (int i = 0; i < 32; i += 8)
        outB[(size_t)(n0 + ty + i) * K + k0 + tx] = __float2bfloat16(t[tx][ty + i]);
}

__global__ __launch_bounds__(256) void w2t_cvt(
    const float* __restrict__ f_W2, __hip_bfloat16* __restrict__ W2t)
{
    int idx = blockIdx.x * 256 + threadIdx.x;
    if (idx >= NW * 16 * HH) return;
    const int m = idx >> 14;
    const int n = (idx >> 10) & 15;
    const int h = idx & 1023;
    const float v = (n < NL) ? f_W2[((size_t)m * HH + h) * NL + n] : 0.f;
    W2t[idx] = __float2bfloat16(v);
}

// ---------------------------------------------------------------------------
// Chord step, bf16 state, f32 accumulation. 1024 blocks x 16 rows each,
// XCD-chunked: XCD k owns rows [2048k, 2048(k+1)) so all +-2^l gathers stay
// inside one batch's 2 MB window (fits the XCD's private 4 MB L2) and the
// SAME XCD re-reads what it wrote last step.
// ---------------------------------------------------------------------------
template<bool LAST>
__global__ __launch_bounds__(256) void chord_bf16(
    const uint2* __restrict__ Vin,   // MM x 64 (4 bf16 per lane-slot)
    const float* __restrict__ Wall,  // MM x NW x 16
    void* __restrict__ Vout,         // bf16 (MM x 64 uint2) or f32 (float4)
    int m)
{
    const int t = threadIdx.x;
    const int bid = blockIdx.x;                      // 1024 blocks
    const int rbase = ((bid & 7) * 128 + (bid >> 3)) * 16;
    const int rq = t >> 6;
    const int e = t & 63;

    #pragma unroll 1
    for (int rr = 0; rr < 4; ++rr) {
        const int r = rbase + rr * 4 + rq;
        const int b = r >> 12;
        const int n = r & (NN - 1);

        const float* wrow = Wall + ((size_t)r * NW + m) * 16;
        const size_t base = (size_t)(b << 12) * 64 + e;

        uint2 s = Vin[(size_t)r * 64 + e];
        float a0, a1, a2, a3;
        unpack2(s.x, a0, a1);
        unpack2(s.y, a2, a3);

        #pragma unroll
        for (int l = 0; l < NL; ++l) {
            const int off = (l == 0) ? 0 : (1 << (l - 1));
            const int cn = (n + off) & (NN - 1);
            const float wv = wrow[l];
            const uint2 x = Vin[base + (size_t)cn * 64];
            float x0, x1, x2, x3;
            unpack2(x.x, x0, x1);
            unpack2(x.y, x2, x3);
            a0 = __builtin_fmaf(wv, x0, a0);
            a1 = __builtin_fmaf(wv, x1, a1);
            a2 = __builtin_fmaf(wv, x2, a2);
            a3 = __builtin_fmaf(wv, x3, a3);
        }

        if constexpr (LAST) {
            float4 o = {a0, a1, a2, a3};
            ((float4*)Vout)[(size_t)r * 64 + e] = o;
        } else {
            uint2 o;
            o.x = pack_bf16_rh(a0, a1);
            o.y = pack_bf16_rh(a2, a3);
            ((uint2*)Vout)[(size_t)r * 64 + e] = o;
        }
    }
}

// ---------------------------------------------------------------------------
extern "C" void kernel_launch(void* const* d_in, const int* in_sizes, int n_in,
                              void* d_out, int out_size, void* d_ws, size_t ws_size,
                              hipStream_t stream)
{
    const float* V      = (const float*)d_in[0];
    const float* input  = (const float*)d_in[1];
    const float* g_W1   = (const float*)d_in[2];
    const float* g_b1   = (const float*)d_in[3];
    const float* g_W2   = (const float*)d_in[4];
    const float* g_b2   = (const float*)d_in[5];
    const float* f_W1   = (const float*)d_in[6];
    const float* f_b1   = (const float*)d_in[7];
    const float* f_W2   = (const float*)d_in[8];
    const float* f_b2   = (const float*)d_in[9];
    float* out = (float*)d_out;

    char* ws = (char*)d_ws;
    size_t o = 0;
    __hip_bfloat16* Vb     = (__hip_bfloat16*)(ws + o); o += (size_t)MM * EE * 2;        // 8 MB
    __hip_bfloat16* Xb     = (__hip_bfloat16*)(ws + o); o += (size_t)MM * EE * 2;        // 8 MB
    __hip_bfloat16* gW1t   = (__hip_bfloat16*)(ws + o); o += (size_t)HH * EE * 2;        // 512 KB
    __hip_bfloat16* gW2t   = (__hip_bfloat16*)(ws + o); o += (size_t)EE * HH * 2;        // 512 KB
    __hip_bfloat16* fW1t   = (__hip_bfloat16*)(ws + o); o += (size_t)NW * HH * EE * 2;   // 6 MB
    __hip_bfloat16* W2tA   = (__hip_bfloat16*)(ws + o); o += (size_t)NW * 16 * HH * 2;   // 384 KB
    float*          Wall   = (float*)(ws + o);          o += (size_t)MM * NW * 16 * 4;   // 12 MB
    __hip_bfloat16* Vg0    = (__hip_bfloat16*)(ws + o); o += (size_t)MM * EE * 2;        // 8 MB
    __hip_bfloat16* Vg1    = (__hip_bfloat16*)(ws + o); o += (size_t)MM * EE * 2;        // 8 MB

    dim3 blk(256);

    // 0. dtype conversion / weight transposes
    cvt_bf16<<<(MM * EE / 4 + 255) / 256, blk, 0, stream>>>(V, Vb, MM * EE / 4);
    cvt_bf16<<<(MM * EE / 4 + 255) / 256, blk, 0, stream>>>(input, Xb, MM * EE / 4);
    transpose_cvt<<<dim3(HH / 32, EE / 32, 1),  blk, 0, stream>>>(g_W1, gW1t, EE, HH);
    transpose_cvt<<<dim3(EE / 32, HH / 32, 1),  blk, 0, stream>>>(g_W2, gW2t, HH, EE);
    transpose_cvt<<<dim3(HH / 32, EE / 32, NW), blk, 0, stream>>>(f_W1, fW1t, EE, HH);
    w2t_cvt<<<(NW * 16 * HH + 255) / 256, blk, 0, stream>>>(f_W2, W2tA);

    // 1. Gate MLP on V, fully fused, bf16 V0 -> Vg0
    gate_fused<<<MM / 64, blk, 0, stream>>>(Vb, gW1t, g_b1, gW2t, g_b2, Vg0);

    // 2. All 12 levels' link weights in ONE fused launch (256 rows/block)
    f_fused<<<dim3(MM / 256, NW), dim3(512), 0, stream>>>(
        Xb, fW1t, f_b1, W2tA, f_b2, Wall);

    // 3. 12 sequential chord steps, stream-ordered; final widens to f32 out
    const __hip_bfloat16* cur = Vg0;
    __hip_bfloat16* nxt = Vg1;
    for (int m = 0; m < NW - 1; ++m) {
        chord_bf16<false><<<1024, blk, 0, stream>>>(
            (const uint2*)cur, Wall, nxt, m);
        __hip_bfloat16* tswap = (__hip_bfloat16*)cur;
        cur = nxt;
        nxt = tswap;
    }
    chord_bf16<true><<<1024, blk, 0, stream>>>(
        (const uint2*)cur, Wall, out, NW - 1);
}

// Round 12
// 345.904 us; speedup vs baseline: 1.2316x; 1.1849x over previous
//
#include <hip/hip_runtime.h>
#include <hip/hip_bf16.h>
#include <math.h>

// Problem constants
#define BB 4
#define NN 4096
#define EE 256
#define HH 1024
#define NW 12
#define NL 13
#define MM (BB * NN)   // 16384 rows

typedef __attribute__((ext_vector_type(8))) short short8;   // 8 bf16 (4 VGPRs)
typedef __attribute__((ext_vector_type(4))) float f32x4;

// Fast gelu, exp2 form: x * sigmoid(1.5957691*(x + 0.044715 x^3)).
__device__ __forceinline__ float gelu_fast(float x) {
    float t = __builtin_fmaf(0.044715f, x * x, 1.0f);
    float e = __builtin_amdgcn_exp2f(-2.3021193f * (x * t));
    return x * __builtin_amdgcn_rcpf(1.0f + e);
}

__device__ __forceinline__ unsigned pack_bf16_rh(float a, float b) {
    unsigned ua = (__builtin_bit_cast(unsigned, a) + 0x8000u) >> 16;
    unsigned ub = (__builtin_bit_cast(unsigned, b) + 0x8000u) & 0xFFFF0000u;
    return ua | ub;
}

__device__ __forceinline__ void unpack2(unsigned u, float& lo, float& hi) {
    lo = __builtin_bit_cast(float, u << 16);
    hi = __builtin_bit_cast(float, u & 0xFFFF0000u);
}

__device__ __forceinline__ void load_lds16(const void* g, void* l) {
    __builtin_amdgcn_global_load_lds(
        (const __attribute__((address_space(1))) void*)g,
        (__attribute__((address_space(3))) void*)l, 16, 0, 0);
}

// ---------------------------------------------------------------------------
// bf16 MFMA GEMM (m97 structure): C[M,N] = op(A[M,K] @ Bt[N,K]^T + bias)
// 128x128 tile, BK=32, 256 threads (4 waves, 2x2). Gate MLP (r7-validated:
// the tiled gemm pair beats a fused gate kernel, whose per-64-row W1
// re-staging costs 128 MB of traffic).
// ---------------------------------------------------------------------------
template<typename OutT, bool GELU>
__global__ __launch_bounds__(256) void gemm_bf16(
    const __hip_bfloat16* __restrict__ A,   // M x K  row-major
    const __hip_bfloat16* __restrict__ Bt,  // N x K  row-major (pre-transposed)
    const float* __restrict__ bias,         // N
    OutT* __restrict__ C,                   // M x N
    int M, int N, int K)
{
    __shared__ __hip_bfloat16 As[128 * 32];
    __shared__ __hip_bfloat16 Bs[128 * 32];

    const int tid = threadIdx.x;
    const int w = tid >> 6, l = tid & 63;
    const int wr = w >> 1, wc = w & 1;       // 2x2 wave grid, each 64x64
    const int row0 = blockIdx.y * 128;
    const int col0 = blockIdx.x * 128;

    const int c0 = w * 64 + l;
    const int c1 = c0 + 256;
    const __hip_bfloat16* gA0 = A  + (size_t)(row0 + (c0 >> 2)) * K + (c0 & 3) * 8;
    const __hip_bfloat16* gA1 = A  + (size_t)(row0 + (c1 >> 2)) * K + (c1 & 3) * 8;
    const __hip_bfloat16* gB0 = Bt + (size_t)(col0 + (c0 >> 2)) * K + (c0 & 3) * 8;
    const __hip_bfloat16* gB1 = Bt + (size_t)(col0 + (c1 >> 2)) * K + (c1 & 3) * 8;
    char* dA0 = (char*)As + w * 1024;
    char* dA1 = (char*)As + w * 1024 + 4096;
    char* dB0 = (char*)Bs + w * 1024;
    char* dB1 = (char*)Bs + w * 1024 + 4096;

    const int lr = l & 15;
    const int lk = (l >> 4) * 8;

    f32x4 acc[4][4] = {};

    for (int k0 = 0; k0 < K; k0 += 32) {
        load_lds16(gA0 + k0, dA0);
        load_lds16(gA1 + k0, dA1);
        load_lds16(gB0 + k0, dB0);
        load_lds16(gB1 + k0, dB1);
        __syncthreads();

        short8 a[4], b[4];
        #pragma unroll
        for (int m = 0; m < 4; ++m)
            a[m] = *(const short8*)&As[(wr * 64 + m * 16 + lr) * 32 + lk];
        #pragma unroll
        for (int n = 0; n < 4; ++n)
            b[n] = *(const short8*)&Bs[(wc * 64 + n * 16 + lr) * 32 + lk];
        #pragma unroll
        for (int m = 0; m < 4; ++m)
            #pragma unroll
            for (int n = 0; n < 4; ++n)
                acc[m][n] = __builtin_amdgcn_mfma_f32_16x16x32_bf16(a[m], b[n], acc[m][n], 0, 0, 0);
        __syncthreads();
    }

    #pragma unroll
    for (int m = 0; m < 4; ++m) {
        #pragma unroll
        for (int n = 0; n < 4; ++n) {
            const int col = col0 + wc * 64 + n * 16 + lr;
            const float bv = bias[col];
            #pragma unroll
            for (int j = 0; j < 4; ++j) {
                const int row = row0 + wr * 64 + m * 16 + (l >> 4) * 4 + j;
                float v = acc[m][n][j] + bv;
                if (GELU) v = gelu_fast(v);
                if constexpr (sizeof(OutT) == 2)
                    C[(size_t)row * N + col] = __float2bfloat16(v);
                else
                    C[(size_t)row * N + col] = v;
            }
        }
    }
}

// ---------------------------------------------------------------------------
// Fused f-level kernel v3 (validated 167 us) + bias-in-accumulator init:
// acc C-in starts at bias so the gelu phase drops 32 v_add per ct.
// ---------------------------------------------------------------------------
__global__ __launch_bounds__(256, 3) void f_fused(
    const __hip_bfloat16* __restrict__ X,     // MM x EE
    const __hip_bfloat16* __restrict__ W1t,   // NW x HH x EE
    const float* __restrict__ b1,             // NW x HH
    const __hip_bfloat16* __restrict__ W2t,   // NW x 16 x HH
    const float* __restrict__ b2,             // NW x NL
    float* __restrict__ Wall)                 // MM x NW x 16
{
    __shared__ __hip_bfloat16 Bs[8 * 64 * 32];        // 32 KB [kk][row][32]
    __shared__ __align__(16) char Gb[4][4096];        // per-wave G [32r][64h]
    __shared__ float biasS[HH];                       // 4 KB

    const int tid = threadIdx.x;
    const int w = tid >> 6, l = tid & 63;
    const int row0 = blockIdx.x * 128;
    const int m_lv = blockIdx.y;
    const int lr = l & 15;
    const int g  = l >> 4;
    const int lk = g * 8;

    const __hip_bfloat16* W1m = W1t + (size_t)m_lv * HH * EE;

    ((float4*)biasS)[tid] = ((const float4*)(b1 + (size_t)m_lv * HH))[tid];

    short8 xf[2][8];
    {
        const __hip_bfloat16* xp0 = X + (size_t)(row0 + w * 32 + lr) * EE + lk;
        #pragma unroll
        for (int kk = 0; kk < 8; ++kk) {
            xf[0][kk] = *(const short8*)(xp0 + kk * 32);
            xf[1][kk] = *(const short8*)(xp0 + 16 * EE + kk * 32);
        }
    }

    const __hip_bfloat16* w2p = W2t + ((size_t)m_lv * 16 + lr) * HH + lk;
    char* Gw = Gb[w];

    f32x4 wacc0 = {}, wacc1 = {};

    #pragma unroll
    for (int rstep = 0; rstep < 8; ++rstep) {
        const int c = rstep * 256 + tid;
        load_lds16(W1m + (size_t)((c >> 2) & 63) * EE + (c >> 8) * 32 + (c & 3) * 8,
                   (char*)Bs + c * 16);
    }
    __syncthreads();

    #pragma unroll 1
    for (int ct = 0; ct < 16; ++ct) {
        // acc C-in = bias (h = ct*64 + ni*16 + g*4 + j, same for both mi)
        f32x4 acc[4][2];
        #pragma unroll
        for (int ni = 0; ni < 4; ++ni) {
            const float4 bv = *(const float4*)&biasS[ct * 64 + ni * 16 + g * 4];
            const f32x4 bi = {bv.x, bv.y, bv.z, bv.w};
            acc[ni][0] = bi;
            acc[ni][1] = bi;
        }
        __builtin_amdgcn_s_setprio(1);
        #pragma unroll
        for (int kk = 0; kk < 8; ++kk) {
            short8 a[4];
            #pragma unroll
            for (int ni = 0; ni < 4; ++ni)
                a[ni] = *(const short8*)((const char*)Bs +
                         (kk * 4096 + ni * 1024 + lr * 64 + g * 16));
            #pragma unroll
            for (int ni = 0; ni < 4; ++ni) {
                acc[ni][0] = __builtin_amdgcn_mfma_f32_16x16x32_bf16(a[ni], xf[0][kk], acc[ni][0], 0, 0, 0);
                acc[ni][1] = __builtin_amdgcn_mfma_f32_16x16x32_bf16(a[ni], xf[1][kk], acc[ni][1], 0, 0, 0);
            }
        }
        __builtin_amdgcn_s_setprio(0);
        __syncthreads();                       // all waves done reading Bs

        if (ct < 15) {
            const __hip_bfloat16* W1n = W1m + (size_t)(ct + 1) * 64 * EE;
            #pragma unroll
            for (int rstep = 0; rstep < 8; ++rstep) {
                const int c = rstep * 256 + tid;
                load_lds16(W1n + (size_t)((c >> 2) & 63) * EE + (c >> 8) * 32 + (c & 3) * 8,
                           (char*)Bs + c * 16);
            }
        }

        // gelu -> bf16 pack -> wave-private swizzled G
        #pragma unroll
        for (int ni = 0; ni < 4; ++ni) {
            #pragma unroll
            for (int mi = 0; mi < 2; ++mi) {
                const int rloc = mi * 16 + lr;
                const float v0 = gelu_fast(acc[ni][mi][0]);
                const float v1 = gelu_fast(acc[ni][mi][1]);
                const float v2 = gelu_fast(acc[ni][mi][2]);
                const float v3 = gelu_fast(acc[ni][mi][3]);
                uint2 pk;
                pk.x = pack_bf16_rh(v0, v1);
                pk.y = pack_bf16_rh(v2, v3);
                const int byte = (rloc * 128 + (ni * 16 + g * 4) * 2) ^ ((rloc & 7) << 4);
                *(uint2*)(Gw + byte) = pk;
            }
        }

        // mini-GEMM: Wall-frag += W2t[ct k-range] x G
        #pragma unroll
        for (int ks2 = 0; ks2 < 2; ++ks2) {
            const short8 aw = *(const short8*)(w2p + ct * 64 + ks2 * 32);
            {
                const int byte = (lr * 128 + (ks2 * 32 + lk) * 2) ^ ((lr & 7) << 4);
                const short8 bg = *(const short8*)(Gw + byte);
                wacc0 = __builtin_amdgcn_mfma_f32_16x16x32_bf16(aw, bg, wacc0, 0, 0, 0);
            }
            {
                const int rloc = 16 + lr;
                const int byte = (rloc * 128 + (ks2 * 32 + lk) * 2) ^ ((rloc & 7) << 4);
                const short8 bg = *(const short8*)(Gw + byte);
                wacc1 = __builtin_amdgcn_mfma_f32_16x16x32_bf16(aw, bg, wacc1, 0, 0, 0);
            }
        }
        __syncthreads();                       // staging drained; Bs ready
    }

    const float* b2m = b2 + m_lv * NL;
    #pragma unroll
    for (int j = 0; j < 4; ++j) {
        const int lval = g * 4 + j;
        const float bv = (lval < NL) ? b2m[lval] : 0.f;
        {
            const int r = row0 + w * 32 + lr;
            Wall[((size_t)r * NW + m_lv) * 16 + lval] = wacc0[j] + bv;
        }
        {
            const int r = row0 + w * 32 + 16 + lr;
            Wall[((size_t)r * NW + m_lv) * 16 + lval] = wacc1[j] + bv;
        }
    }
}

// ---------------------------------------------------------------------------
// Converters
// ---------------------------------------------------------------------------
struct bf4 { __hip_bfloat16 a, b, c, d; };

__global__ __launch_bounds__(256) void cvt_bf16(
    const float* __restrict__ in, __hip_bfloat16* __restrict__ out, int n4)
{
    int i = blockIdx.x * 256 + threadIdx.x;
    if (i >= n4) return;
    float4 v = ((const float4*)in)[i];
    bf4 o;
    o.a = __float2bfloat16(v.x); o.b = __float2bfloat16(v.y);
    o.c = __float2bfloat16(v.z); o.d = __float2bfloat16(v.w);
    ((bf4*)out)[i] = o;
}

__global__ __launch_bounds__(256) void transpose_cvt(
    const float* __restrict__ in, __hip_bfloat16* __restrict__ out, int K, int N)
{
    __shared__ float t[32][33];
    const int bz = blockIdx.z;
    const float* inB = in + (size_t)bz * K * N;
    __hip_bfloat16* outB = out + (size_t)bz * K * N;
    const int n0 = blockIdx.x * 32, k0 = blockIdx.y * 32;
    const int tx = threadIdx.x & 31, ty = threadIdx.x >> 5;
    #pragma unroll
    for (int i = 0; i < 32; i += 8)
        t[ty + i][tx] = inB[(size_t)(k0 + ty + i) * N + n0 + tx];
    __syncthreads();
    #pragma unroll
    for (int i = 0; i < 32; i += 8)
        outB[(size_t)(n0 + ty + i) * K + k0 + tx] = __float2bfloat16(t[tx][ty + i]);
}

__global__ __launch_bounds__(256) void w2t_cvt(
    const float* __restrict__ f_W2, __hip_bfloat16* __restrict__ W2t)
{
    int idx = blockIdx.x * 256 + threadIdx.x;
    if (idx >= NW * 16 * HH) return;
    const int m = idx >> 14;
    const int n = (idx >> 10) & 15;
    const int h = idx & 1023;
    const float v = (n < NL) ? f_W2[((size_t)m * HH + h) * NL + n] : 0.f;
    W2t[idx] = __float2bfloat16(v);
}

// ---------------------------------------------------------------------------
// Chord step, bf16 state, f32 accumulation, 2 rows/thread with INTERLEAVED
// gathers (26 outstanding loads: latency-bound kernel, double the MLP).
// 2048 blocks x 256 threads; block covers rows [bid*8, bid*8+8).
// ---------------------------------------------------------------------------
template<bool LAST>
__global__ __launch_bounds__(256) void chord_bf16(
    const uint2* __restrict__ Vin,   // MM x 64 (4 bf16 per lane-slot)
    const float* __restrict__ Wall,  // MM x NW x 16
    void* __restrict__ Vout,         // bf16 (MM x 64 uint2) or f32 (float4)
    int m)
{
    const int t = threadIdx.x;
    const int rq = t >> 6;
    const int e = t & 63;
    const int rA = blockIdx.x * 8 + rq;
    const int rB = rA + 4;
    const int b = rA >> 12;                  // rB same batch (rA%4096 < 4092)
    const int nA = rA & (NN - 1);
    const int nB = rB & (NN - 1);

    const float* wrowA = Wall + ((size_t)rA * NW + m) * 16;
    const float* wrowB = Wall + ((size_t)rB * NW + m) * 16;
    const size_t base = (size_t)(b << 12) * 64 + e;

    uint2 sA = Vin[(size_t)rA * 64 + e];
    uint2 sB = Vin[(size_t)rB * 64 + e];
    float a0, a1, a2, a3, c0, c1, c2, c3;
    unpack2(sA.x, a0, a1); unpack2(sA.y, a2, a3);
    unpack2(sB.x, c0, c1); unpack2(sB.y, c2, c3);

    #pragma unroll
    for (int l = 0; l < NL; ++l) {
        const int off = (l == 0) ? 0 : (1 << (l - 1));
        const int cnA = (nA + off) & (NN - 1);
        const int cnB = (nB + off) & (NN - 1);
        const float wvA = wrowA[l];
        const float wvB = wrowB[l];
        const uint2 xA = Vin[base + (size_t)cnA * 64];
        const uint2 xB = Vin[base + (size_t)cnB * 64];
        float x0, x1, x2, x3;
        unpack2(xA.x, x0, x1); unpack2(xA.y, x2, x3);
        a0 = __builtin_fmaf(wvA, x0, a0);
        a1 = __builtin_fmaf(wvA, x1, a1);
        a2 = __builtin_fmaf(wvA, x2, a2);
        a3 = __builtin_fmaf(wvA, x3, a3);
        unpack2(xB.x, x0, x1); unpack2(xB.y, x2, x3);
        c0 = __builtin_fmaf(wvB, x0, c0);
        c1 = __builtin_fmaf(wvB, x1, c1);
        c2 = __builtin_fmaf(wvB, x2, c2);
        c3 = __builtin_fmaf(wvB, x3, c3);
    }

    if constexpr (LAST) {
        float4 oA = {a0, a1, a2, a3};
        float4 oB = {c0, c1, c2, c3};
        ((float4*)Vout)[(size_t)rA * 64 + e] = oA;
        ((float4*)Vout)[(size_t)rB * 64 + e] = oB;
    } else {
        uint2 oA, oB;
        oA.x = pack_bf16_rh(a0, a1); oA.y = pack_bf16_rh(a2, a3);
        oB.x = pack_bf16_rh(c0, c1); oB.y = pack_bf16_rh(c2, c3);
        ((uint2*)Vout)[(size_t)rA * 64 + e] = oA;
        ((uint2*)Vout)[(size_t)rB * 64 + e] = oB;
    }
}

// ---------------------------------------------------------------------------
extern "C" void kernel_launch(void* const* d_in, const int* in_sizes, int n_in,
                              void* d_out, int out_size, void* d_ws, size_t ws_size,
                              hipStream_t stream)
{
    const float* V      = (const float*)d_in[0];
    const float* input  = (const float*)d_in[1];
    const float* g_W1   = (const float*)d_in[2];
    const float* g_b1   = (const float*)d_in[3];
    const float* g_W2   = (const float*)d_in[4];
    const float* g_b2   = (const float*)d_in[5];
    const float* f_W1   = (const float*)d_in[6];
    const float* f_b1   = (const float*)d_in[7];
    const float* f_W2   = (const float*)d_in[8];
    const float* f_b2   = (const float*)d_in[9];
    float* out = (float*)d_out;

    char* ws = (char*)d_ws;
    size_t o = 0;
    __hip_bfloat16* Vb     = (__hip_bfloat16*)(ws + o); o += (size_t)MM * EE * 2;        // 8 MB
    __hip_bfloat16* Xb     = (__hip_bfloat16*)(ws + o); o += (size_t)MM * EE * 2;        // 8 MB
    __hip_bfloat16* gW1t   = (__hip_bfloat16*)(ws + o); o += (size_t)HH * EE * 2;        // 512 KB
    __hip_bfloat16* gW2t   = (__hip_bfloat16*)(ws + o); o += (size_t)EE * HH * 2;        // 512 KB
    __hip_bfloat16* fW1t   = (__hip_bfloat16*)(ws + o); o += (size_t)NW * HH * EE * 2;   // 6 MB
    __hip_bfloat16* W2tA   = (__hip_bfloat16*)(ws + o); o += (size_t)NW * 16 * HH * 2;   // 384 KB
    __hip_bfloat16* Whb    = (__hip_bfloat16*)(ws + o); o += (size_t)MM * HH * 2;        // 32 MB (gate only)
    float*          Wall   = (float*)(ws + o);          o += (size_t)MM * NW * 16 * 4;   // 12 MB
    __hip_bfloat16* Vg0    = (__hip_bfloat16*)(ws + o); o += (size_t)MM * EE * 2;        // 8 MB
    __hip_bfloat16* Vg1    = (__hip_bfloat16*)(ws + o); o += (size_t)MM * EE * 2;        // 8 MB

    dim3 blk(256);

    // 0. dtype conversion / weight transposes
    cvt_bf16<<<(MM * EE / 4 + 255) / 256, blk, 0, stream>>>(V, Vb, MM * EE / 4);
    cvt_bf16<<<(MM * EE / 4 + 255) / 256, blk, 0, stream>>>(input, Xb, MM * EE / 4);
    transpose_cvt<<<dim3(HH / 32, EE / 32, 1),  blk, 0, stream>>>(g_W1, gW1t, EE, HH);
    transpose_cvt<<<dim3(EE / 32, HH / 32, 1),  blk, 0, stream>>>(g_W2, gW2t, HH, EE);
    transpose_cvt<<<dim3(HH / 32, EE / 32, NW), blk, 0, stream>>>(f_W1, fW1t, EE, HH);
    w2t_cvt<<<(NW * 16 * HH + 255) / 256, blk, 0, stream>>>(f_W2, W2tA);

    // 1-2. Gate MLP on V via tiled gemm pair (r7-validated best)
    gemm_bf16<__hip_bfloat16, true><<<dim3(HH / 128, MM / 128), blk, 0, stream>>>(
        Vb, gW1t, g_b1, Whb, MM, HH, EE);
    gemm_bf16<__hip_bfloat16, false><<<dim3(EE / 128, MM / 128), blk, 0, stream>>>(
        Whb, gW2t, g_b2, Vg0, MM, EE, HH);

    // 3. All 12 levels' link weights in ONE fused launch
    f_fused<<<dim3(MM / 128, NW), blk, 0, stream>>>(Xb, fW1t, f_b1, W2tA, f_b2, Wall);

    // 4. 12 sequential chord steps, stream-ordered; final widens to f32 out
    const __hip_bfloat16* cur = Vg0;
    __hip_bfloat16* nxt = Vg1;
    for (int m = 0; m < NW - 1; ++m) {
        chord_bf16<false><<<MM / 8, blk, 0, stream>>>(
            (const uint2*)cur, Wall, nxt, m);
        __hip_bfloat16* tswap = (__hip_bfloat16*)cur;
        cur = nxt;
        nxt = tswap;
    }
    chord_bf16<true><<<MM / 8, blk, 0, stream>>>(
        (const uint2*)cur, Wall, out, NW - 1);
}

// Round 13
// 342.011 us; speedup vs baseline: 1.2456x; 1.0114x over previous
//
#include <hip/hip_runtime.h>
#include <hip/hip_bf16.h>
#include <math.h>

// Problem constants
#define BB 4
#define NN 4096
#define EE 256
#define HH 1024
#define NW 12
#define NL 13
#define MM (BB * NN)   // 16384 rows

typedef __attribute__((ext_vector_type(8))) short short8;   // 8 bf16 (4 VGPRs)
typedef __attribute__((ext_vector_type(4))) float f32x4;

// Fast gelu, exp2 form: x * sigmoid(1.5957691*(x + 0.044715 x^3)).
__device__ __forceinline__ float gelu_fast(float x) {
    float t = __builtin_fmaf(0.044715f, x * x, 1.0f);
    float e = __builtin_amdgcn_exp2f(-2.3021193f * (x * t));
    return x * __builtin_amdgcn_rcpf(1.0f + e);
}

__device__ __forceinline__ unsigned pack_bf16_rh(float a, float b) {
    unsigned ua = (__builtin_bit_cast(unsigned, a) + 0x8000u) >> 16;
    unsigned ub = (__builtin_bit_cast(unsigned, b) + 0x8000u) & 0xFFFF0000u;
    return ua | ub;
}

__device__ __forceinline__ void unpack2(unsigned u, float& lo, float& hi) {
    lo = __builtin_bit_cast(float, u << 16);
    hi = __builtin_bit_cast(float, u & 0xFFFF0000u);
}

__device__ __forceinline__ void load_lds16(const void* g, void* l) {
    __builtin_amdgcn_global_load_lds(
        (const __attribute__((address_space(1))) void*)g,
        (__attribute__((address_space(3))) void*)l, 16, 0, 0);
}

// ---------------------------------------------------------------------------
// bf16 MFMA GEMM (m97 structure): C[M,N] = op(A[M,K] @ Bt[N,K]^T + bias)
// 128x128 tile, BK=32, 256 threads (4 waves, 2x2). Gate MLP.
// ---------------------------------------------------------------------------
template<typename OutT, bool GELU>
__global__ __launch_bounds__(256) void gemm_bf16(
    const __hip_bfloat16* __restrict__ A,   // M x K  row-major
    const __hip_bfloat16* __restrict__ Bt,  // N x K  row-major (pre-transposed)
    const float* __restrict__ bias,         // N
    OutT* __restrict__ C,                   // M x N
    int M, int N, int K)
{
    __shared__ __hip_bfloat16 As[128 * 32];
    __shared__ __hip_bfloat16 Bs[128 * 32];

    const int tid = threadIdx.x;
    const int w = tid >> 6, l = tid & 63;
    const int wr = w >> 1, wc = w & 1;       // 2x2 wave grid, each 64x64
    const int row0 = blockIdx.y * 128;
    const int col0 = blockIdx.x * 128;

    const int c0 = w * 64 + l;
    const int c1 = c0 + 256;
    const __hip_bfloat16* gA0 = A  + (size_t)(row0 + (c0 >> 2)) * K + (c0 & 3) * 8;
    const __hip_bfloat16* gA1 = A  + (size_t)(row0 + (c1 >> 2)) * K + (c1 & 3) * 8;
    const __hip_bfloat16* gB0 = Bt + (size_t)(col0 + (c0 >> 2)) * K + (c0 & 3) * 8;
    const __hip_bfloat16* gB1 = Bt + (size_t)(col0 + (c1 >> 2)) * K + (c1 & 3) * 8;
    char* dA0 = (char*)As + w * 1024;
    char* dA1 = (char*)As + w * 1024 + 4096;
    char* dB0 = (char*)Bs + w * 1024;
    char* dB1 = (char*)Bs + w * 1024 + 4096;

    const int lr = l & 15;
    const int lk = (l >> 4) * 8;

    f32x4 acc[4][4] = {};

    for (int k0 = 0; k0 < K; k0 += 32) {
        load_lds16(gA0 + k0, dA0);
        load_lds16(gA1 + k0, dA1);
        load_lds16(gB0 + k0, dB0);
        load_lds16(gB1 + k0, dB1);
        __syncthreads();

        short8 a[4], b[4];
        #pragma unroll
        for (int m = 0; m < 4; ++m)
            a[m] = *(const short8*)&As[(wr * 64 + m * 16 + lr) * 32 + lk];
        #pragma unroll
        for (int n = 0; n < 4; ++n)
            b[n] = *(const short8*)&Bs[(wc * 64 + n * 16 + lr) * 32 + lk];
        #pragma unroll
        for (int m = 0; m < 4; ++m)
            #pragma unroll
            for (int n = 0; n < 4; ++n)
                acc[m][n] = __builtin_amdgcn_mfma_f32_16x16x32_bf16(a[m], b[n], acc[m][n], 0, 0, 0);
        __syncthreads();
    }

    #pragma unroll
    for (int m = 0; m < 4; ++m) {
        #pragma unroll
        for (int n = 0; n < 4; ++n) {
            const int col = col0 + wc * 64 + n * 16 + lr;
            const float bv = bias[col];
            #pragma unroll
            for (int j = 0; j < 4; ++j) {
                const int row = row0 + wr * 64 + m * 16 + (l >> 4) * 4 + j;
                float v = acc[m][n][j] + bv;
                if (GELU) v = gelu_fast(v);
                if constexpr (sizeof(OutT) == 2)
                    C[(size_t)row * N + col] = __float2bfloat16(v);
                else
                    C[(size_t)row * N + col] = v;
            }
        }
    }
}

// ---------------------------------------------------------------------------
// Fused f-level kernel v3 + bias-in-accumulator (validated 156 us).
// ---------------------------------------------------------------------------
__global__ __launch_bounds__(256, 3) void f_fused(
    const __hip_bfloat16* __restrict__ X,     // MM x EE
    const __hip_bfloat16* __restrict__ W1t,   // NW x HH x EE
    const float* __restrict__ b1,             // NW x HH
    const __hip_bfloat16* __restrict__ W2t,   // NW x 16 x HH
    const float* __restrict__ b2,             // NW x NL
    float* __restrict__ Wall)                 // MM x NW x 16
{
    __shared__ __hip_bfloat16 Bs[8 * 64 * 32];        // 32 KB [kk][row][32]
    __shared__ __align__(16) char Gb[4][4096];        // per-wave G [32r][64h]
    __shared__ float biasS[HH];                       // 4 KB

    const int tid = threadIdx.x;
    const int w = tid >> 6, l = tid & 63;
    const int row0 = blockIdx.x * 128;
    const int m_lv = blockIdx.y;
    const int lr = l & 15;
    const int g  = l >> 4;
    const int lk = g * 8;

    const __hip_bfloat16* W1m = W1t + (size_t)m_lv * HH * EE;

    ((float4*)biasS)[tid] = ((const float4*)(b1 + (size_t)m_lv * HH))[tid];

    short8 xf[2][8];
    {
        const __hip_bfloat16* xp0 = X + (size_t)(row0 + w * 32 + lr) * EE + lk;
        #pragma unroll
        for (int kk = 0; kk < 8; ++kk) {
            xf[0][kk] = *(const short8*)(xp0 + kk * 32);
            xf[1][kk] = *(const short8*)(xp0 + 16 * EE + kk * 32);
        }
    }

    const __hip_bfloat16* w2p = W2t + ((size_t)m_lv * 16 + lr) * HH + lk;
    char* Gw = Gb[w];

    f32x4 wacc0 = {}, wacc1 = {};

    #pragma unroll
    for (int rstep = 0; rstep < 8; ++rstep) {
        const int c = rstep * 256 + tid;
        load_lds16(W1m + (size_t)((c >> 2) & 63) * EE + (c >> 8) * 32 + (c & 3) * 8,
                   (char*)Bs + c * 16);
    }
    __syncthreads();

    #pragma unroll 1
    for (int ct = 0; ct < 16; ++ct) {
        // acc C-in = bias (h = ct*64 + ni*16 + g*4 + j, same for both mi)
        f32x4 acc[4][2];
        #pragma unroll
        for (int ni = 0; ni < 4; ++ni) {
            const float4 bv = *(const float4*)&biasS[ct * 64 + ni * 16 + g * 4];
            const f32x4 bi = {bv.x, bv.y, bv.z, bv.w};
            acc[ni][0] = bi;
            acc[ni][1] = bi;
        }
        __builtin_amdgcn_s_setprio(1);
        #pragma unroll
        for (int kk = 0; kk < 8; ++kk) {
            short8 a[4];
            #pragma unroll
            for (int ni = 0; ni < 4; ++ni)
                a[ni] = *(const short8*)((const char*)Bs +
                         (kk * 4096 + ni * 1024 + lr * 64 + g * 16));
            #pragma unroll
            for (int ni = 0; ni < 4; ++ni) {
                acc[ni][0] = __builtin_amdgcn_mfma_f32_16x16x32_bf16(a[ni], xf[0][kk], acc[ni][0], 0, 0, 0);
                acc[ni][1] = __builtin_amdgcn_mfma_f32_16x16x32_bf16(a[ni], xf[1][kk], acc[ni][1], 0, 0, 0);
            }
        }
        __builtin_amdgcn_s_setprio(0);
        __syncthreads();                       // all waves done reading Bs

        if (ct < 15) {
            const __hip_bfloat16* W1n = W1m + (size_t)(ct + 1) * 64 * EE;
            #pragma unroll
            for (int rstep = 0; rstep < 8; ++rstep) {
                const int c = rstep * 256 + tid;
                load_lds16(W1n + (size_t)((c >> 2) & 63) * EE + (c >> 8) * 32 + (c & 3) * 8,
                           (char*)Bs + c * 16);
            }
        }

        // gelu -> bf16 pack -> wave-private swizzled G
        #pragma unroll
        for (int ni = 0; ni < 4; ++ni) {
            #pragma unroll
            for (int mi = 0; mi < 2; ++mi) {
                const int rloc = mi * 16 + lr;
                const float v0 = gelu_fast(acc[ni][mi][0]);
                const float v1 = gelu_fast(acc[ni][mi][1]);
                const float v2 = gelu_fast(acc[ni][mi][2]);
                const float v3 = gelu_fast(acc[ni][mi][3]);
                uint2 pk;
                pk.x = pack_bf16_rh(v0, v1);
                pk.y = pack_bf16_rh(v2, v3);
                const int byte = (rloc * 128 + (ni * 16 + g * 4) * 2) ^ ((rloc & 7) << 4);
                *(uint2*)(Gw + byte) = pk;
            }
        }

        // mini-GEMM: Wall-frag += W2t[ct k-range] x G
        #pragma unroll
        for (int ks2 = 0; ks2 < 2; ++ks2) {
            const short8 aw = *(const short8*)(w2p + ct * 64 + ks2 * 32);
            {
                const int byte = (lr * 128 + (ks2 * 32 + lk) * 2) ^ ((lr & 7) << 4);
                const short8 bg = *(const short8*)(Gw + byte);
                wacc0 = __builtin_amdgcn_mfma_f32_16x16x32_bf16(aw, bg, wacc0, 0, 0, 0);
            }
            {
                const int rloc = 16 + lr;
                const int byte = (rloc * 128 + (ks2 * 32 + lk) * 2) ^ ((rloc & 7) << 4);
                const short8 bg = *(const short8*)(Gw + byte);
                wacc1 = __builtin_amdgcn_mfma_f32_16x16x32_bf16(aw, bg, wacc1, 0, 0, 0);
            }
        }
        __syncthreads();                       // staging drained; Bs ready
    }

    const float* b2m = b2 + m_lv * NL;
    #pragma unroll
    for (int j = 0; j < 4; ++j) {
        const int lval = g * 4 + j;
        const float bv = (lval < NL) ? b2m[lval] : 0.f;
        {
            const int r = row0 + w * 32 + lr;
            Wall[((size_t)r * NW + m_lv) * 16 + lval] = wacc0[j] + bv;
        }
        {
            const int r = row0 + w * 32 + 16 + lr;
            Wall[((size_t)r * NW + m_lv) * 16 + lval] = wacc1[j] + bv;
        }
    }
}

// ---------------------------------------------------------------------------
// One prep kernel for ALL conversions/transposes (was 6 launches).
// Block ranges:
//   [0,4096)        cvt V   -> Vb
//   [4096,8192)     cvt input -> Xb
//   [8192,8448)     transpose g_W1 (K=256,N=1024)  -> gW1t
//   [8448,8704)     transpose g_W2 (K=1024,N=256)  -> gW2t
//   [8704,11776)    transpose f_W1 12 x (K=256,N=1024) -> fW1t
//   [11776,12544)   f_W2 -> W2tA (padded 13->16, transposed)
// ---------------------------------------------------------------------------
struct bf4 { __hip_bfloat16 a, b, c, d; };

__device__ __forceinline__ void cvt_body(
    const float* __restrict__ in, __hip_bfloat16* __restrict__ out, int i)
{
    float4 v = ((const float4*)in)[i];
    bf4 o;
    o.a = __float2bfloat16(v.x); o.b = __float2bfloat16(v.y);
    o.c = __float2bfloat16(v.z); o.d = __float2bfloat16(v.w);
    ((bf4*)out)[i] = o;
}

__device__ __forceinline__ void transpose_body(
    const float* __restrict__ inB, __hip_bfloat16* __restrict__ outB,
    int K, int N, int bx, int by, float (*t)[33])
{
    const int n0 = bx * 32, k0 = by * 32;
    const int tx = threadIdx.x & 31, ty = threadIdx.x >> 5;  // 32 x 8
    #pragma unroll
    for (int i = 0; i < 32; i += 8)
        t[ty + i][tx] = inB[(size_t)(k0 + ty + i) * N + n0 + tx];
    __syncthreads();
    #pragma unroll
    for (int i = 0; i < 32; i += 8)
        outB[(size_t)(n0 + ty + i) * K + k0 + tx] = __float2bfloat16(t[tx][ty + i]);
}

__global__ __launch_bounds__(256) void prep_all(
    const float* __restrict__ V, const float* __restrict__ input,
    const float* __restrict__ g_W1, const float* __restrict__ g_W2,
    const float* __restrict__ f_W1, const float* __restrict__ f_W2,
    __hip_bfloat16* __restrict__ Vb, __hip_bfloat16* __restrict__ Xb,
    __hip_bfloat16* __restrict__ gW1t, __hip_bfloat16* __restrict__ gW2t,
    __hip_bfloat16* __restrict__ fW1t, __hip_bfloat16* __restrict__ W2tA)
{
    __shared__ float t[32][33];
    const int bid = blockIdx.x;
    const int tid = threadIdx.x;

    if (bid < 4096) {
        cvt_body(V, Vb, bid * 256 + tid);
    } else if (bid < 8192) {
        cvt_body(input, Xb, (bid - 4096) * 256 + tid);
    } else if (bid < 8448) {
        const int b2 = bid - 8192;                   // g_W1: grid (32, 8)
        transpose_body(g_W1, gW1t, EE, HH, b2 & 31, b2 >> 5, t);
    } else if (bid < 8704) {
        const int b2 = bid - 8448;                   // g_W2: grid (8, 32)
        transpose_body(g_W2, gW2t, HH, EE, b2 & 7, b2 >> 3, t);
    } else if (bid < 11776) {
        const int b2 = bid - 8704;                   // f_W1: 12 x (32, 8)
        const int z = b2 >> 8, r = b2 & 255;
        transpose_body(f_W1 + (size_t)z * EE * HH, fW1t + (size_t)z * HH * EE,
                       EE, HH, r & 31, r >> 5, t);
    } else {
        const int idx = (bid - 11776) * 256 + tid;   // w2t: NW*16*HH elems
        const int m = idx >> 14;
        const int n = (idx >> 10) & 15;
        const int h = idx & 1023;
        const float v = (n < NL) ? f_W2[((size_t)m * HH + h) * NL + n] : 0.f;
        W2tA[idx] = __float2bfloat16(v);
    }
}

// ---------------------------------------------------------------------------
// Chord step, bf16 state, f32 accumulation, 4 rows/thread fully interleaved
// (52 outstanding gathers -- latency-bound kernel). 1024 blocks x 16 rows.
// ---------------------------------------------------------------------------
template<bool LAST>
__global__ __launch_bounds__(256) void chord_bf16(
    const uint2* __restrict__ Vin,   // MM x 64 (4 bf16 per lane-slot)
    const float* __restrict__ Wall,  // MM x NW x 16
    void* __restrict__ Vout,         // bf16 (MM x 64 uint2) or f32 (float4)
    int m)
{
    const int t = threadIdx.x;
    const int rq = t >> 6;
    const int e = t & 63;
    const int r0 = blockIdx.x * 16 + rq;     // rows r0, r0+4, r0+8, r0+12
    const int b = r0 >> 12;                  // block never crosses a batch
    const size_t base = (size_t)(b << 12) * 64 + e;

    int n[4];
    const float* wrow[4];
    float a[4][4];
    #pragma unroll
    for (int i = 0; i < 4; ++i) {
        const int r = r0 + i * 4;
        n[i] = r & (NN - 1);
        wrow[i] = Wall + ((size_t)r * NW + m) * 16;
        const uint2 s = Vin[(size_t)r * 64 + e];
        unpack2(s.x, a[i][0], a[i][1]);
        unpack2(s.y, a[i][2], a[i][3]);
    }

    #pragma unroll
    for (int l = 0; l < NL; ++l) {
        const int off = (l == 0) ? 0 : (1 << (l - 1));
        uint2 x[4];
        float wv[4];
        #pragma unroll
        for (int i = 0; i < 4; ++i) {
            const int cn = (n[i] + off) & (NN - 1);
            x[i] = Vin[base + (size_t)cn * 64];
            wv[i] = wrow[i][l];
        }
        #pragma unroll
        for (int i = 0; i < 4; ++i) {
            float x0, x1, x2, x3;
            unpack2(x[i].x, x0, x1);
            unpack2(x[i].y, x2, x3);
            a[i][0] = __builtin_fmaf(wv[i], x0, a[i][0]);
            a[i][1] = __builtin_fmaf(wv[i], x1, a[i][1]);
            a[i][2] = __builtin_fmaf(wv[i], x2, a[i][2]);
            a[i][3] = __builtin_fmaf(wv[i], x3, a[i][3]);
        }
    }

    #pragma unroll
    for (int i = 0; i < 4; ++i) {
        const int r = r0 + i * 4;
        if constexpr (LAST) {
            float4 o = {a[i][0], a[i][1], a[i][2], a[i][3]};
            ((float4*)Vout)[(size_t)r * 64 + e] = o;
        } else {
            uint2 o;
            o.x = pack_bf16_rh(a[i][0], a[i][1]);
            o.y = pack_bf16_rh(a[i][2], a[i][3]);
            ((uint2*)Vout)[(size_t)r * 64 + e] = o;
        }
    }
}

// ---------------------------------------------------------------------------
extern "C" void kernel_launch(void* const* d_in, const int* in_sizes, int n_in,
                              void* d_out, int out_size, void* d_ws, size_t ws_size,
                              hipStream_t stream)
{
    const float* V      = (const float*)d_in[0];
    const float* input  = (const float*)d_in[1];
    const float* g_W1   = (const float*)d_in[2];
    const float* g_b1   = (const float*)d_in[3];
    const float* g_W2   = (const float*)d_in[4];
    const float* g_b2   = (const float*)d_in[5];
    const float* f_W1   = (const float*)d_in[6];
    const float* f_b1   = (const float*)d_in[7];
    const float* f_W2   = (const float*)d_in[8];
    const float* f_b2   = (const float*)d_in[9];
    float* out = (float*)d_out;

    char* ws = (char*)d_ws;
    size_t o = 0;
    __hip_bfloat16* Vb     = (__hip_bfloat16*)(ws + o); o += (size_t)MM * EE * 2;        // 8 MB
    __hip_bfloat16* Xb     = (__hip_bfloat16*)(ws + o); o += (size_t)MM * EE * 2;        // 8 MB
    __hip_bfloat16* gW1t   = (__hip_bfloat16*)(ws + o); o += (size_t)HH * EE * 2;        // 512 KB
    __hip_bfloat16* gW2t   = (__hip_bfloat16*)(ws + o); o += (size_t)EE * HH * 2;        // 512 KB
    __hip_bfloat16* fW1t   = (__hip_bfloat16*)(ws + o); o += (size_t)NW * HH * EE * 2;   // 6 MB
    __hip_bfloat16* W2tA   = (__hip_bfloat16*)(ws + o); o += (size_t)NW * 16 * HH * 2;   // 384 KB
    __hip_bfloat16* Whb    = (__hip_bfloat16*)(ws + o); o += (size_t)MM * HH * 2;        // 32 MB (gate only)
    float*          Wall   = (float*)(ws + o);          o += (size_t)MM * NW * 16 * 4;   // 12 MB
    __hip_bfloat16* Vg0    = (__hip_bfloat16*)(ws + o); o += (size_t)MM * EE * 2;        // 8 MB
    __hip_bfloat16* Vg1    = (__hip_bfloat16*)(ws + o); o += (size_t)MM * EE * 2;        // 8 MB

    dim3 blk(256);

    // 0. ALL dtype conversion / weight transposes in one launch
    prep_all<<<12544, blk, 0, stream>>>(V, input, g_W1, g_W2, f_W1, f_W2,
                                        Vb, Xb, gW1t, gW2t, fW1t, W2tA);

    // 1-2. Gate MLP on V via tiled gemm pair (r7-validated best)
    gemm_bf16<__hip_bfloat16, true><<<dim3(HH / 128, MM / 128), blk, 0, stream>>>(
        Vb, gW1t, g_b1, Whb, MM, HH, EE);
    gemm_bf16<__hip_bfloat16, false><<<dim3(EE / 128, MM / 128), blk, 0, stream>>>(
        Whb, gW2t, g_b2, Vg0, MM, EE, HH);

    // 3. All 12 levels' link weights in ONE fused launch
    f_fused<<<dim3(MM / 128, NW), blk, 0, stream>>>(Xb, fW1t, f_b1, W2tA, f_b2, Wall);

    // 4. 12 sequential chord steps, stream-ordered; final widens to f32 out
    const __hip_bfloat16* cur = Vg0;
    __hip_bfloat16* nxt = Vg1;
    for (int m = 0; m < NW - 1; ++m) {
        chord_bf16<false><<<MM / 16, blk, 0, stream>>>(
            (const uint2*)cur, Wall, nxt, m);
        __hip_bfloat16* tswap = (__hip_bfloat16*)cur;
        cur = nxt;
        nxt = tswap;
    }
    chord_bf16<true><<<MM / 16, blk, 0, stream>>>(
        (const uint2*)cur, Wall, out, NW - 1);
}

// Round 14
// 331.387 us; speedup vs baseline: 1.2855x; 1.0321x over previous
//
#include <hip/hip_runtime.h>
#include <hip/hip_bf16.h>
#include <math.h>

// Problem constants
#define BB 4
#define NN 4096
#define EE 256
#define HH 1024
#define NW 12
#define NL 13
#define MM (BB * NN)   // 16384 rows

typedef __attribute__((ext_vector_type(8))) short short8;   // 8 bf16 (4 VGPRs)
typedef __attribute__((ext_vector_type(4))) float f32x4;

// Fast gelu, exp2 form: x * sigmoid(1.5957691*(x + 0.044715 x^3)).
__device__ __forceinline__ float gelu_fast(float x) {
    float t = __builtin_fmaf(0.044715f, x * x, 1.0f);
    float e = __builtin_amdgcn_exp2f(-2.3021193f * (x * t));
    return x * __builtin_amdgcn_rcpf(1.0f + e);
}

__device__ __forceinline__ unsigned pack_bf16_rh(float a, float b) {
    unsigned ua = (__builtin_bit_cast(unsigned, a) + 0x8000u) >> 16;
    unsigned ub = (__builtin_bit_cast(unsigned, b) + 0x8000u) & 0xFFFF0000u;
    return ua | ub;
}

// HW packed f32->2xbf16 (RNE). 1 VALU op vs ~4-5 for the arith pack.
__device__ __forceinline__ unsigned cvt_pk_bf16(float a, float b) {
    unsigned r;
    asm("v_cvt_pk_bf16_f32 %0, %1, %2" : "=v"(r) : "v"(a), "v"(b));
    return r;
}

__device__ __forceinline__ void unpack2(unsigned u, float& lo, float& hi) {
    lo = __builtin_bit_cast(float, u << 16);
    hi = __builtin_bit_cast(float, u & 0xFFFF0000u);
}

__device__ __forceinline__ void load_lds16(const void* g, void* l) {
    __builtin_amdgcn_global_load_lds(
        (const __attribute__((address_space(1))) void*)g,
        (__attribute__((address_space(3))) void*)l, 16, 0, 0);
}

// ---------------------------------------------------------------------------
// bf16 MFMA GEMM (m97 structure): C[M,N] = op(A[M,K] @ Bt[N,K]^T + bias)
// 128x128 tile, BK=32, 256 threads. Used for gate gemm2 (K=1024).
// ---------------------------------------------------------------------------
template<typename OutT, bool GELU>
__global__ __launch_bounds__(256) void gemm_bf16(
    const __hip_bfloat16* __restrict__ A,   // M x K  row-major
    const __hip_bfloat16* __restrict__ Bt,  // N x K  row-major (pre-transposed)
    const float* __restrict__ bias,         // N
    OutT* __restrict__ C,                   // M x N
    int M, int N, int K)
{
    __shared__ __hip_bfloat16 As[128 * 32];
    __shared__ __hip_bfloat16 Bs[128 * 32];

    const int tid = threadIdx.x;
    const int w = tid >> 6, l = tid & 63;
    const int wr = w >> 1, wc = w & 1;       // 2x2 wave grid, each 64x64
    const int row0 = blockIdx.y * 128;
    const int col0 = blockIdx.x * 128;

    const int c0 = w * 64 + l;
    const int c1 = c0 + 256;
    const __hip_bfloat16* gA0 = A  + (size_t)(row0 + (c0 >> 2)) * K + (c0 & 3) * 8;
    const __hip_bfloat16* gA1 = A  + (size_t)(row0 + (c1 >> 2)) * K + (c1 & 3) * 8;
    const __hip_bfloat16* gB0 = Bt + (size_t)(col0 + (c0 >> 2)) * K + (c0 & 3) * 8;
    const __hip_bfloat16* gB1 = Bt + (size_t)(col0 + (c1 >> 2)) * K + (c1 & 3) * 8;
    char* dA0 = (char*)As + w * 1024;
    char* dA1 = (char*)As + w * 1024 + 4096;
    char* dB0 = (char*)Bs + w * 1024;
    char* dB1 = (char*)Bs + w * 1024 + 4096;

    const int lr = l & 15;
    const int lk = (l >> 4) * 8;

    f32x4 acc[4][4] = {};

    for (int k0 = 0; k0 < K; k0 += 32) {
        load_lds16(gA0 + k0, dA0);
        load_lds16(gA1 + k0, dA1);
        load_lds16(gB0 + k0, dB0);
        load_lds16(gB1 + k0, dB1);
        __syncthreads();

        short8 a[4], b[4];
        #pragma unroll
        for (int m = 0; m < 4; ++m)
            a[m] = *(const short8*)&As[(wr * 64 + m * 16 + lr) * 32 + lk];
        #pragma unroll
        for (int n = 0; n < 4; ++n)
            b[n] = *(const short8*)&Bs[(wc * 64 + n * 16 + lr) * 32 + lk];
        #pragma unroll
        for (int m = 0; m < 4; ++m)
            #pragma unroll
            for (int n = 0; n < 4; ++n)
                acc[m][n] = __builtin_amdgcn_mfma_f32_16x16x32_bf16(a[m], b[n], acc[m][n], 0, 0, 0);
        __syncthreads();
    }

    #pragma unroll
    for (int m = 0; m < 4; ++m) {
        #pragma unroll
        for (int n = 0; n < 4; ++n) {
            const int col = col0 + wc * 64 + n * 16 + lr;
            const float bv = bias[col];
            #pragma unroll
            for (int j = 0; j < 4; ++j) {
                const int row = row0 + wr * 64 + m * 16 + (l >> 4) * 4 + j;
                float v = acc[m][n][j] + bv;
                if (GELU) v = gelu_fast(v);
                if constexpr (sizeof(OutT) == 2)
                    C[(size_t)row * N + col] = __float2bfloat16(v);
                else
                    C[(size_t)row * N + col] = v;
            }
        }
    }
}

// ---------------------------------------------------------------------------
// Gate gemm1 with A-in-registers (f_fused machinery minus W2):
// Wh = gelu(Vb @ W1 + b1). X rows in regs, full-K W1 staging per 64-col
// tile (ct=0,1), gelu+cvt_pk into wave-private swizzled G, then coalesced
// 16B/lane stores (avoids the swapped-D scatter-store problem).
// ---------------------------------------------------------------------------
__global__ __launch_bounds__(256, 3) void gemm1_areg(
    const __hip_bfloat16* __restrict__ A,     // MM x EE (Vb)
    const __hip_bfloat16* __restrict__ W1t,   // HH x EE
    const float* __restrict__ b1,             // HH
    __hip_bfloat16* __restrict__ Wh)          // MM x HH
{
    __shared__ __hip_bfloat16 Bs[8 * 64 * 32];   // 32 KB [kk][row][32]
    __shared__ __align__(16) char Gb[4][4096];   // per-wave G [32r][64h]

    const int tid = threadIdx.x;
    const int w = tid >> 6, l = tid & 63;
    const int row0 = blockIdx.x * 128;
    const int col0 = blockIdx.y * 128;
    const int lr = l & 15, g = l >> 4, lk = g * 8;

    short8 xf[2][8];
    {
        const __hip_bfloat16* xp0 = A + (size_t)(row0 + w * 32 + lr) * EE + lk;
        #pragma unroll
        for (int kk = 0; kk < 8; ++kk) {
            xf[0][kk] = *(const short8*)(xp0 + kk * 32);
            xf[1][kk] = *(const short8*)(xp0 + 16 * EE + kk * 32);
        }
    }
    char* Gw = Gb[w];

    // prologue: stage ct=0 (chunk c: kk=c>>8, row=(c>>2)&63, g=c&3)
    #pragma unroll
    for (int rstep = 0; rstep < 8; ++rstep) {
        const int c = rstep * 256 + tid;
        load_lds16(W1t + (size_t)(col0 + ((c >> 2) & 63)) * EE + (c >> 8) * 32 + (c & 3) * 8,
                   (char*)Bs + c * 16);
    }
    __syncthreads();

    #pragma unroll 1
    for (int ct = 0; ct < 2; ++ct) {
        f32x4 acc[4][2];
        #pragma unroll
        for (int ni = 0; ni < 4; ++ni) {
            const float4 bv = *(const float4*)&b1[col0 + ct * 64 + ni * 16 + g * 4];
            const f32x4 bi = {bv.x, bv.y, bv.z, bv.w};
            acc[ni][0] = bi;
            acc[ni][1] = bi;
        }
        __builtin_amdgcn_s_setprio(1);
        #pragma unroll
        for (int kk = 0; kk < 8; ++kk) {
            short8 a[4];
            #pragma unroll
            for (int ni = 0; ni < 4; ++ni)
                a[ni] = *(const short8*)((const char*)Bs +
                         (kk * 4096 + ni * 1024 + lr * 64 + g * 16));
            #pragma unroll
            for (int ni = 0; ni < 4; ++ni) {
                acc[ni][0] = __builtin_amdgcn_mfma_f32_16x16x32_bf16(a[ni], xf[0][kk], acc[ni][0], 0, 0, 0);
                acc[ni][1] = __builtin_amdgcn_mfma_f32_16x16x32_bf16(a[ni], xf[1][kk], acc[ni][1], 0, 0, 0);
            }
        }
        __builtin_amdgcn_s_setprio(0);
        __syncthreads();                       // all waves done reading Bs

        if (ct == 0) {
            #pragma unroll
            for (int rstep = 0; rstep < 8; ++rstep) {
                const int c = rstep * 256 + tid;
                load_lds16(W1t + (size_t)(col0 + 64 + ((c >> 2) & 63)) * EE + (c >> 8) * 32 + (c & 3) * 8,
                           (char*)Bs + c * 16);
            }
        }

        // gelu -> bf16 (cvt_pk) -> wave-private swizzled G
        #pragma unroll
        for (int ni = 0; ni < 4; ++ni) {
            #pragma unroll
            for (int mi = 0; mi < 2; ++mi) {
                const int rloc = mi * 16 + lr;
                const float v0 = gelu_fast(acc[ni][mi][0]);
                const float v1 = gelu_fast(acc[ni][mi][1]);
                const float v2 = gelu_fast(acc[ni][mi][2]);
                const float v3 = gelu_fast(acc[ni][mi][3]);
                uint2 pk;
                pk.x = cvt_pk_bf16(v0, v1);
                pk.y = cvt_pk_bf16(v2, v3);
                const int byte = (rloc * 128 + (ni * 16 + g * 4) * 2) ^ ((rloc & 7) << 4);
                *(uint2*)(Gw + byte) = pk;
            }
        }

        // coalesced store: 4 passes x (8 rows x 128B); G is wave-private
        #pragma unroll
        for (int p = 0; p < 4; ++p) {
            const int rl = p * 8 + (l >> 3);
            const int hb = (l & 7) * 16;
            const uint4 v = *(const uint4*)(Gw + ((rl * 128 + hb) ^ ((rl & 7) << 4)));
            *(uint4*)((char*)(Wh + (size_t)(row0 + w * 32 + rl) * HH + col0 + ct * 64) + hb) = v;
        }
        __syncthreads();                       // staging drained; Bs ready
    }
}

// ---------------------------------------------------------------------------
// Fused f-level kernel v3 + bias-in-acc + cvt_pk pack.
// ---------------------------------------------------------------------------
__global__ __launch_bounds__(256, 3) void f_fused(
    const __hip_bfloat16* __restrict__ X,     // MM x EE
    const __hip_bfloat16* __restrict__ W1t,   // NW x HH x EE
    const float* __restrict__ b1,             // NW x HH
    const __hip_bfloat16* __restrict__ W2t,   // NW x 16 x HH
    const float* __restrict__ b2,             // NW x NL
    float* __restrict__ Wall)                 // MM x NW x 16
{
    __shared__ __hip_bfloat16 Bs[8 * 64 * 32];        // 32 KB [kk][row][32]
    __shared__ __align__(16) char Gb[4][4096];        // per-wave G [32r][64h]
    __shared__ float biasS[HH];                       // 4 KB

    const int tid = threadIdx.x;
    const int w = tid >> 6, l = tid & 63;
    const int row0 = blockIdx.x * 128;
    const int m_lv = blockIdx.y;
    const int lr = l & 15;
    const int g  = l >> 4;
    const int lk = g * 8;

    const __hip_bfloat16* W1m = W1t + (size_t)m_lv * HH * EE;

    ((float4*)biasS)[tid] = ((const float4*)(b1 + (size_t)m_lv * HH))[tid];

    short8 xf[2][8];
    {
        const __hip_bfloat16* xp0 = X + (size_t)(row0 + w * 32 + lr) * EE + lk;
        #pragma unroll
        for (int kk = 0; kk < 8; ++kk) {
            xf[0][kk] = *(const short8*)(xp0 + kk * 32);
            xf[1][kk] = *(const short8*)(xp0 + 16 * EE + kk * 32);
        }
    }

    const __hip_bfloat16* w2p = W2t + ((size_t)m_lv * 16 + lr) * HH + lk;
    char* Gw = Gb[w];

    f32x4 wacc0 = {}, wacc1 = {};

    #pragma unroll
    for (int rstep = 0; rstep < 8; ++rstep) {
        const int c = rstep * 256 + tid;
        load_lds16(W1m + (size_t)((c >> 2) & 63) * EE + (c >> 8) * 32 + (c & 3) * 8,
                   (char*)Bs + c * 16);
    }
    __syncthreads();

    #pragma unroll 1
    for (int ct = 0; ct < 16; ++ct) {
        // acc C-in = bias
        f32x4 acc[4][2];
        #pragma unroll
        for (int ni = 0; ni < 4; ++ni) {
            const float4 bv = *(const float4*)&biasS[ct * 64 + ni * 16 + g * 4];
            const f32x4 bi = {bv.x, bv.y, bv.z, bv.w};
            acc[ni][0] = bi;
            acc[ni][1] = bi;
        }
        __builtin_amdgcn_s_setprio(1);
        #pragma unroll
        for (int kk = 0; kk < 8; ++kk) {
            short8 a[4];
            #pragma unroll
            for (int ni = 0; ni < 4; ++ni)
                a[ni] = *(const short8*)((const char*)Bs +
                         (kk * 4096 + ni * 1024 + lr * 64 + g * 16));
            #pragma unroll
            for (int ni = 0; ni < 4; ++ni) {
                acc[ni][0] = __builtin_amdgcn_mfma_f32_16x16x32_bf16(a[ni], xf[0][kk], acc[ni][0], 0, 0, 0);
                acc[ni][1] = __builtin_amdgcn_mfma_f32_16x16x32_bf16(a[ni], xf[1][kk], acc[ni][1], 0, 0, 0);
            }
        }
        __builtin_amdgcn_s_setprio(0);
        __syncthreads();                       // all waves done reading Bs

        if (ct < 15) {
            const __hip_bfloat16* W1n = W1m + (size_t)(ct + 1) * 64 * EE;
            #pragma unroll
            for (int rstep = 0; rstep < 8; ++rstep) {
                const int c = rstep * 256 + tid;
                load_lds16(W1n + (size_t)((c >> 2) & 63) * EE + (c >> 8) * 32 + (c & 3) * 8,
                           (char*)Bs + c * 16);
            }
        }

        // gelu -> bf16 (cvt_pk) -> wave-private swizzled G
        #pragma unroll
        for (int ni = 0; ni < 4; ++ni) {
            #pragma unroll
            for (int mi = 0; mi < 2; ++mi) {
                const int rloc = mi * 16 + lr;
                const float v0 = gelu_fast(acc[ni][mi][0]);
                const float v1 = gelu_fast(acc[ni][mi][1]);
                const float v2 = gelu_fast(acc[ni][mi][2]);
                const float v3 = gelu_fast(acc[ni][mi][3]);
                uint2 pk;
                pk.x = cvt_pk_bf16(v0, v1);
                pk.y = cvt_pk_bf16(v2, v3);
                const int byte = (rloc * 128 + (ni * 16 + g * 4) * 2) ^ ((rloc & 7) << 4);
                *(uint2*)(Gw + byte) = pk;
            }
        }

        // mini-GEMM: Wall-frag += W2t[ct k-range] x G
        #pragma unroll
        for (int ks2 = 0; ks2 < 2; ++ks2) {
            const short8 aw = *(const short8*)(w2p + ct * 64 + ks2 * 32);
            {
                const int byte = (lr * 128 + (ks2 * 32 + lk) * 2) ^ ((lr & 7) << 4);
                const short8 bg = *(const short8*)(Gw + byte);
                wacc0 = __builtin_amdgcn_mfma_f32_16x16x32_bf16(aw, bg, wacc0, 0, 0, 0);
            }
            {
                const int rloc = 16 + lr;
                const int byte = (rloc * 128 + (ks2 * 32 + lk) * 2) ^ ((rloc & 7) << 4);
                const short8 bg = *(const short8*)(Gw + byte);
                wacc1 = __builtin_amdgcn_mfma_f32_16x16x32_bf16(aw, bg, wacc1, 0, 0, 0);
            }
        }
        __syncthreads();                       // staging drained; Bs ready
    }

    const float* b2m = b2 + m_lv * NL;
    #pragma unroll
    for (int j = 0; j < 4; ++j) {
        const int lval = g * 4 + j;
        const float bv = (lval < NL) ? b2m[lval] : 0.f;
        {
            const int r = row0 + w * 32 + lr;
            Wall[((size_t)r * NW + m_lv) * 16 + lval] = wacc0[j] + bv;
        }
        {
            const int r = row0 + w * 32 + 16 + lr;
            Wall[((size_t)r * NW + m_lv) * 16 + lval] = wacc1[j] + bv;
        }
    }
}

// ---------------------------------------------------------------------------
// One prep kernel for ALL conversions/transposes.
// ---------------------------------------------------------------------------
struct bf4 { __hip_bfloat16 a, b, c, d; };

__device__ __forceinline__ void cvt_body(
    const float* __restrict__ in, __hip_bfloat16* __restrict__ out, int i)
{
    float4 v = ((const float4*)in)[i];
    bf4 o;
    o.a = __float2bfloat16(v.x); o.b = __float2bfloat16(v.y);
    o.c = __float2bfloat16(v.z); o.d = __float2bfloat16(v.w);
    ((bf4*)out)[i] = o;
}

__device__ __forceinline__ void transpose_body(
    const float* __restrict__ inB, __hip_bfloat16* __restrict__ outB,
    int K, int N, int bx, int by, float (*t)[33])
{
    const int n0 = bx * 32, k0 = by * 32;
    const int tx = threadIdx.x & 31, ty = threadIdx.x >> 5;  // 32 x 8
    #pragma unroll
    for (int i = 0; i < 32; i += 8)
        t[ty + i][tx] = inB[(size_t)(k0 + ty + i) * N + n0 + tx];
    __syncthreads();
    #pragma unroll
    for (int i = 0; i < 32; i += 8)
        outB[(size_t)(n0 + ty + i) * K + k0 + tx] = __float2bfloat16(t[tx][ty + i]);
}

__global__ __launch_bounds__(256) void prep_all(
    const float* __restrict__ V, const float* __restrict__ input,
    const float* __restrict__ g_W1, const float* __restrict__ g_W2,
    const float* __restrict__ f_W1, const float* __restrict__ f_W2,
    __hip_bfloat16* __restrict__ Vb, __hip_bfloat16* __restrict__ Xb,
    __hip_bfloat16* __restrict__ gW1t, __hip_bfloat16* __restrict__ gW2t,
    __hip_bfloat16* __restrict__ fW1t, __hip_bfloat16* __restrict__ W2tA)
{
    __shared__ float t[32][33];
    const int bid = blockIdx.x;
    const int tid = threadIdx.x;

    if (bid < 4096) {
        cvt_body(V, Vb, bid * 256 + tid);
    } else if (bid < 8192) {
        cvt_body(input, Xb, (bid - 4096) * 256 + tid);
    } else if (bid < 8448) {
        const int b2 = bid - 8192;                   // g_W1: grid (32, 8)
        transpose_body(g_W1, gW1t, EE, HH, b2 & 31, b2 >> 5, t);
    } else if (bid < 8704) {
        const int b2 = bid - 8448;                   // g_W2: grid (8, 32)
        transpose_body(g_W2, gW2t, HH, EE, b2 & 7, b2 >> 3, t);
    } else if (bid < 11776) {
        const int b2 = bid - 8704;                   // f_W1: 12 x (32, 8)
        const int z = b2 >> 8, r = b2 & 255;
        transpose_body(f_W1 + (size_t)z * EE * HH, fW1t + (size_t)z * HH * EE,
                       EE, HH, r & 31, r >> 5, t);
    } else {
        const int idx = (bid - 11776) * 256 + tid;   // w2t: NW*16*HH elems
        const int m = idx >> 14;
        const int n = (idx >> 10) & 15;
        const int h = idx & 1023;
        const float v = (n < NL) ? f_W2[((size_t)m * HH + h) * NL + n] : 0.f;
        W2tA[idx] = __float2bfloat16(v);
    }
}

// ---------------------------------------------------------------------------
// Chord step, bf16 state, f32 accumulation, 4 rows/thread fully interleaved.
// ---------------------------------------------------------------------------
template<bool LAST>
__global__ __launch_bounds__(256) void chord_bf16(
    const uint2* __restrict__ Vin,   // MM x 64 (4 bf16 per lane-slot)
    const float* __restrict__ Wall,  // MM x NW x 16
    void* __restrict__ Vout,         // bf16 (MM x 64 uint2) or f32 (float4)
    int m)
{
    const int t = threadIdx.x;
    const int rq = t >> 6;
    const int e = t & 63;
    const int r0 = blockIdx.x * 16 + rq;     // rows r0, r0+4, r0+8, r0+12
    const int b = r0 >> 12;                  // block never crosses a batch
    const size_t base = (size_t)(b << 12) * 64 + e;

    int n[4];
    const float* wrow[4];
    float a[4][4];
    #pragma unroll
    for (int i = 0; i < 4; ++i) {
        const int r = r0 + i * 4;
        n[i] = r & (NN - 1);
        wrow[i] = Wall + ((size_t)r * NW + m) * 16;
        const uint2 s = Vin[(size_t)r * 64 + e];
        unpack2(s.x, a[i][0], a[i][1]);
        unpack2(s.y, a[i][2], a[i][3]);
    }

    #pragma unroll
    for (int l = 0; l < NL; ++l) {
        const int off = (l == 0) ? 0 : (1 << (l - 1));
        uint2 x[4];
        float wv[4];
        #pragma unroll
        for (int i = 0; i < 4; ++i) {
            const int cn = (n[i] + off) & (NN - 1);
            x[i] = Vin[base + (size_t)cn * 64];
            wv[i] = wrow[i][l];
        }
        #pragma unroll
        for (int i = 0; i < 4; ++i) {
            float x0, x1, x2, x3;
            unpack2(x[i].x, x0, x1);
            unpack2(x[i].y, x2, x3);
            a[i][0] = __builtin_fmaf(wv[i], x0, a[i][0]);
            a[i][1] = __builtin_fmaf(wv[i], x1, a[i][1]);
            a[i][2] = __builtin_fmaf(wv[i], x2, a[i][2]);
            a[i][3] = __builtin_fmaf(wv[i], x3, a[i][3]);
        }
    }

    #pragma unroll
    for (int i = 0; i < 4; ++i) {
        const int r = r0 + i * 4;
        if constexpr (LAST) {
            float4 o = {a[i][0], a[i][1], a[i][2], a[i][3]};
            ((float4*)Vout)[(size_t)r * 64 + e] = o;
        } else {
            uint2 o;
            o.x = pack_bf16_rh(a[i][0], a[i][1]);
            o.y = pack_bf16_rh(a[i][2], a[i][3]);
            ((uint2*)Vout)[(size_t)r * 64 + e] = o;
        }
    }
}

// ---------------------------------------------------------------------------
extern "C" void kernel_launch(void* const* d_in, const int* in_sizes, int n_in,
                              void* d_out, int out_size, void* d_ws, size_t ws_size,
                              hipStream_t stream)
{
    const float* V      = (const float*)d_in[0];
    const float* input  = (const float*)d_in[1];
    const float* g_W1   = (const float*)d_in[2];
    const float* g_b1   = (const float*)d_in[3];
    const float* g_W2   = (const float*)d_in[4];
    const float* g_b2   = (const float*)d_in[5];
    const float* f_W1   = (const float*)d_in[6];
    const float* f_b1   = (const float*)d_in[7];
    const float* f_W2   = (const float*)d_in[8];
    const float* f_b2   = (const float*)d_in[9];
    float* out = (float*)d_out;

    char* ws = (char*)d_ws;
    size_t o = 0;
    __hip_bfloat16* Vb     = (__hip_bfloat16*)(ws + o); o += (size_t)MM * EE * 2;        // 8 MB
    __hip_bfloat16* Xb     = (__hip_bfloat16*)(ws + o); o += (size_t)MM * EE * 2;        // 8 MB
    __hip_bfloat16* gW1t   = (__hip_bfloat16*)(ws + o); o += (size_t)HH * EE * 2;        // 512 KB
    __hip_bfloat16* gW2t   = (__hip_bfloat16*)(ws + o); o += (size_t)EE * HH * 2;        // 512 KB
    __hip_bfloat16* fW1t   = (__hip_bfloat16*)(ws + o); o += (size_t)NW * HH * EE * 2;   // 6 MB
    __hip_bfloat16* W2tA   = (__hip_bfloat16*)(ws + o); o += (size_t)NW * 16 * HH * 2;   // 384 KB
    __hip_bfloat16* Whb    = (__hip_bfloat16*)(ws + o); o += (size_t)MM * HH * 2;        // 32 MB (gate only)
    float*          Wall   = (float*)(ws + o);          o += (size_t)MM * NW * 16 * 4;   // 12 MB
    __hip_bfloat16* Vg0    = (__hip_bfloat16*)(ws + o); o += (size_t)MM * EE * 2;        // 8 MB
    __hip_bfloat16* Vg1    = (__hip_bfloat16*)(ws + o); o += (size_t)MM * EE * 2;        // 8 MB

    dim3 blk(256);

    // 0. ALL dtype conversion / weight transposes in one launch
    prep_all<<<12544, blk, 0, stream>>>(V, input, g_W1, g_W2, f_W1, f_W2,
                                        Vb, Xb, gW1t, gW2t, fW1t, W2tA);

    // 1. Gate gemm1: A-in-registers variant (K=256)
    gemm1_areg<<<dim3(MM / 128, HH / 128), blk, 0, stream>>>(Vb, gW1t, g_b1, Whb);
    // 2. Gate gemm2 (K=1024), bf16 out -> Vg0
    gemm_bf16<__hip_bfloat16, false><<<dim3(EE / 128, MM / 128), blk, 0, stream>>>(
        Whb, gW2t, g_b2, Vg0, MM, EE, HH);

    // 3. All 12 levels' link weights in ONE fused launch
    f_fused<<<dim3(MM / 128, NW), blk, 0, stream>>>(Xb, fW1t, f_b1, W2tA, f_b2, Wall);

    // 4. 12 sequential chord steps, stream-ordered; final widens to f32 out
    const __hip_bfloat16* cur = Vg0;
    __hip_bfloat16* nxt = Vg1;
    for (int m = 0; m < NW - 1; ++m) {
        chord_bf16<false><<<MM / 16, blk, 0, stream>>>(
            (const uint2*)cur, Wall, nxt, m);
        __hip_bfloat16* tswap = (__hip_bfloat16*)cur;
        cur = nxt;
        nxt = tswap;
    }
    chord_bf16<true><<<MM / 16, blk, 0, stream>>>(
        (const uint2*)cur, Wall, out, NW - 1);
}